// Round 20
// baseline (244.009 us; speedup 1.0000x reference)
//
#include <hip/hip_runtime.h>

typedef unsigned short u16;
typedef __attribute__((ext_vector_type(8))) short bf16x8;   // 8 x bf16 (4 VGPRs)
typedef __attribute__((ext_vector_type(4))) short s16x4;
typedef __attribute__((ext_vector_type(4))) float f32x4;

#define DEV __device__ __forceinline__

DEV u16 f2bf(float f) {                       // fp32 -> bf16 bits, RNE
  union { float f; unsigned u; } v; v.f = f;
  unsigned r = v.u + 0x7fffu + ((v.u >> 16) & 1u);
  return (u16)(r >> 16);
}
DEV u16 f2bf_tr(float f) {                    // truncating (P only; bias cancels in O/l)
  union { float f; unsigned u; } v; v.f = f;
  return (u16)(v.u >> 16);
}

// XOR bank-swizzle for a 64-col bf16 LDS tile (u16 index units).
DEV int swzi(int row, int col) { return row * 64 + (col ^ ((row & 7) << 3)); }

// async global->LDS, 16B per lane. LDS dest is wave-uniform base; HW adds lane*16.
DEV void gl16(const u16* g, u16* l) {
  __builtin_amdgcn_global_load_lds((const __attribute__((address_space(1))) void*)g,
                                   (__attribute__((address_space(3))) void*)l, 16, 0, 0);
}

template <int N> DEV void waitv() {           // counted vmcnt (compile-time imm)
  asm volatile("s_waitcnt vmcnt(%0)" :: "n"(N) : "memory");
}
DEV void barrier_f() {
  __builtin_amdgcn_s_barrier();
  asm volatile("" ::: "memory");
}
DEV void lgkm0() { asm volatile("s_waitcnt lgkmcnt(0)" ::: "memory"); }

// ---- weight cast + transpose: w[K][N] f32 -> wt[N][K] bf16 ----------------
__global__ __launch_bounds__(256) void wcastT(const float* __restrict__ w,
                                              u16* __restrict__ wt, int K, int N) {
  __shared__ float t[32][33];
  int n0 = blockIdx.x * 32, k0 = blockIdx.y * 32;
  int tx = threadIdx.x & 31, ty = threadIdx.x >> 5;
#pragma unroll
  for (int i = 0; i < 32; i += 8)
    t[ty + i][tx] = w[(size_t)(k0 + ty + i) * N + n0 + tx];
  __syncthreads();
#pragma unroll
  for (int i = 0; i < 32; i += 8)
    wt[(size_t)(n0 + ty + i) * K + k0 + tx] = f2bf(t[tx][ty + i]);
}

// ---- LayerNorm (1024 cols, no affine) f32 -> bf16 -------------------------
__global__ __launch_bounds__(256) void ln_kernel(const float* __restrict__ x,
                                                 u16* __restrict__ out) {
  int row = blockIdx.x, tid = threadIdx.x;
  const float4* xr = (const float4*)(x + (size_t)row * 1024);
  float4 f = xr[tid];
  float s = f.x + f.y + f.z + f.w;
  float s2 = f.x * f.x + f.y * f.y + f.z * f.z + f.w * f.w;
#pragma unroll
  for (int o = 1; o < 64; o <<= 1) { s += __shfl_xor(s, o); s2 += __shfl_xor(s2, o); }
  __shared__ float red[2][4];
  int wid = tid >> 6;
  if ((tid & 63) == 0) { red[0][wid] = s; red[1][wid] = s2; }
  __syncthreads();
  float tot  = red[0][0] + red[0][1] + red[0][2] + red[0][3];
  float tot2 = red[1][0] + red[1][1] + red[1][2] + red[1][3];
  float mu = tot * (1.0f / 1024.0f);
  float var = tot2 * (1.0f / 1024.0f) - mu * mu;
  float rstd = rsqrtf(var + 1e-5f);
  s16x4 o4;
  o4[0] = (short)f2bf((f.x - mu) * rstd);
  o4[1] = (short)f2bf((f.y - mu) * rstd);
  o4[2] = (short)f2bf((f.z - mu) * rstd);
  o4[3] = (short)f2bf((f.w - mu) * rstd);
  *(s16x4*)(out + (size_t)row * 1024 + tid * 4) = o4;
}

// ---- GEMM: C[M,N] = A[M,K](bf16) * Bt[N,K]^T(bf16), fused epilogues -------
// R15/R17-proven structure. fc/mlp2: BM=64/BK=64 (measured best).
// MODE 1: outF = resid + C (f32)        MODE 3: outF = resid + bias + C
template <int MODE, int BM, int BK>
__global__ __launch_bounds__(256) void gemm_bt(
    const u16* __restrict__ A, const u16* __restrict__ Bt, int N, int K,
    const float* __restrict__ resid, const float* __restrict__ bias,
    float* __restrict__ outF) {
  constexpr int MR = BM / 32;
  constexpr int KH = BK / 32;
  constexpr int LDEPTH = KH * (BM / 64 + 2);
  constexpr int ACH = BM * 32, BCH = 128 * 32;
  __shared__ __align__(16) u16 lA[2 * KH * ACH];
  __shared__ __align__(16) u16 lB[2 * KH * BCH];
  int tid = threadIdx.x;
  int lane = tid & 63, wid = tid >> 6;
  int lr = lane & 15, lg = lane >> 4;

  int gx = gridDim.x;
  int nwg = gx * gridDim.y;
  int bid = blockIdx.y * gx + blockIdx.x;
  int swz = (bid & 7) * (nwg >> 3) + (bid >> 3);
  int rowBase = (swz / gx) * BM, colBase = (swz % gx) * 128;
  int wr = (wid >> 1) * (MR * 16), wc = (wid & 1) * 64;

  int srow = wid * 16 + (lane >> 2);
  int scol = (lane & 3) * 8;
  const u16* gA = A + (size_t)(rowBase + srow) * K + scol;
  const u16* gB = Bt + (size_t)(colBase + srow) * K + scol;
  u16* lAb = &lA[wid * 16 * 32];
  u16* lBb = &lB[wid * 16 * 32];

  auto stage = [&](int t, int buf) {
    int k0 = t * BK;
#pragma unroll
    for (int kk = 0; kk < KH; kk++) {
      u16* dA = lAb + buf * KH * ACH + kk * ACH;
      u16* dB = lBb + buf * KH * BCH + kk * BCH;
      int koff = k0 + kk * 32;
#pragma unroll
      for (int c = 0; c < BM / 64; c++)
        gl16(gA + (size_t)c * 64 * K + koff, dA + c * 64 * 32);
#pragma unroll
      for (int c = 0; c < 2; c++)
        gl16(gB + (size_t)c * 64 * K + koff, dB + c * 64 * 32);
    }
  };

  f32x4 acc[MR][4];
  f32x4 zero = {0.f, 0.f, 0.f, 0.f};
#pragma unroll
  for (int m = 0; m < MR; m++)
#pragma unroll
    for (int n = 0; n < 4; n++) acc[m][n] = zero;

  stage(0, 0);

  int nt = K / BK;
  for (int t = 0; t < nt; t++) {
    int cur = t & 1;
    if (t + 1 < nt) {
      stage(t + 1, cur ^ 1);
      waitv<LDEPTH>();
    } else {
      waitv<0>();
    }
    barrier_f();

    const u16* cA = &lA[cur * KH * ACH];
    const u16* cB = &lB[cur * KH * BCH];
#pragma unroll
    for (int kk = 0; kk < KH; kk++) {
      bf16x8 af[MR], bfv[4];
#pragma unroll
      for (int m = 0; m < MR; m++)
        af[m] = *(const bf16x8*)&cA[kk * ACH + (wr + m * 16 + lr) * 32 + lg * 8];
#pragma unroll
      for (int n = 0; n < 4; n++)
        bfv[n] = *(const bf16x8*)&cB[kk * BCH + (wc + n * 16 + lr) * 32 + lg * 8];
#pragma unroll
      for (int m = 0; m < MR; m++)
#pragma unroll
        for (int n = 0; n < 4; n++)
          acc[m][n] = __builtin_amdgcn_mfma_f32_16x16x32_bf16(bfv[n], af[m], acc[m][n], 0, 0, 0);
    }
    barrier_f();
  }

#pragma unroll
  for (int m = 0; m < MR; m++) {
    int grow = rowBase + wr + m * 16 + lr;
#pragma unroll
    for (int n = 0; n < 4; n++) {
      int gcol = colBase + wc + n * 16 + lg * 4;
      f32x4 v4 = acc[m][n];
      if constexpr (MODE == 1) {
        size_t idx = (size_t)grow * N + gcol;
        float4 r = *(const float4*)&resid[idx];
        float4 ov = {r.x + v4[0], r.y + v4[1], r.z + v4[2], r.w + v4[3]};
        *(float4*)&outF[idx] = ov;
      } else {
        size_t idx = (size_t)grow * N + gcol;
        float4 r = *(const float4*)&resid[idx];
        float4 bq = *(const float4*)&bias[gcol];
        float4 ov = {r.x + bq.x + v4[0], r.y + bq.y + v4[1],
                     r.z + bq.z + v4[2], r.w + bq.w + v4[3]};
        *(float4*)&outF[idx] = ov;
      }
    }
  }
}

// ---- 256x256 4-phase pipelined GEMM (R18-measured best), K=1024 -----------
// 8 waves (2Mx4N), wave tile 128x64. K-tile 64 as two [256][32] u16 chunks
// per operand (64B stride = conflict-free b128 reads; gl16 dest linear).
// 4 phases/tile = one C-quadrant x K=64 = 16 MFMA between barriers + setprio.
// Counted waits: vmcnt<2> in p4 (retires t+1's A0,A1,B0), vmcnt<4> in p1
// (retires t+1's B1); each validated by that phase's closing barrier before
// the consuming phase's pre-barrier ds_reads. WAR: stage of t+1 into buf
// (t+1)&1 follows t-1's final closing barrier.
// MODE 0: qkv split -> q(o0, pre-scaled 0.125*log2e), k(o1), V^T direct (o2)
// MODE 2: o0 = gelu(C + bias) bf16
template <int MODE>
__global__ __launch_bounds__(512, 1) void gemm256p(
    const u16* __restrict__ A, const u16* __restrict__ Bt, int N,
    const float* __restrict__ bias,
    u16* __restrict__ o0, u16* __restrict__ o1, u16* __restrict__ o2) {
  constexpr int K = 1024, NT = 16;
  __shared__ __align__(16) u16 lA[2 * 2 * 256 * 32];  // [buf][kh][256][32] 64KB
  __shared__ __align__(16) u16 lB[2 * 2 * 256 * 32];  // 64KB
  int tid = threadIdx.x;
  int lane = tid & 63, wid = tid >> 6;
  int lr = lane & 15, lg = lane >> 4;
  int wm = wid >> 2, wn = wid & 3;                    // 2M x 4N wave grid

  int gx = gridDim.x;
  int nwg = gx * gridDim.y;                           // 192 or 256 (%8==0)
  int bid = blockIdx.y * gx + blockIdx.x;
  int swz = (bid & 7) * (nwg >> 3) + (bid >> 3);
  int rowBase = (swz / gx) * 256, colBase = (swz % gx) * 256;

  int sr0 = tid >> 2, sc = (tid & 3) * 8;             // staging: 128 rows/round
  const u16* gA = A + (size_t)(rowBase + sr0) * K + sc;
  const u16* gB = Bt + (size_t)(colBase + sr0) * K + sc;
  u16* lAw = lA + wid * 512;                          // wave-uniform base
  u16* lBw = lB + wid * 512;

  auto stageA = [&](int t, int kh) {                  // 2 gl16 / thread
    int koff = t * 64 + kh * 32;
    u16* d = lAw + ((t & 1) * 2 + kh) * 8192;
    gl16(gA + koff, d);
    gl16(gA + (size_t)128 * K + koff, d + 4096);
  };
  auto stageB = [&](int t, int kh) {
    int koff = t * 64 + kh * 32;
    u16* d = lBw + ((t & 1) * 2 + kh) * 8192;
    gl16(gB + koff, d);
    gl16(gB + (size_t)128 * K + koff, d + 4096);
  };

  f32x4 acc[8][4];
  f32x4 zero = {0.f, 0.f, 0.f, 0.f};
#pragma unroll
  for (int m = 0; m < 8; m++)
#pragma unroll
    for (int n = 0; n < 4; n++) acc[m][n] = zero;

  bf16x8 aF[4][2], bF0[2][2], bF1[2][2];              // operand frags

  auto rdA = [&](int t, int rh) {                     // 8 ds_read_b128
#pragma unroll
    for (int kh = 0; kh < 2; kh++) {
      const u16* p = lA + ((t & 1) * 2 + kh) * 8192;
#pragma unroll
      for (int m = 0; m < 4; m++)
        aF[m][kh] = *(const bf16x8*)&p[(wm * 128 + rh * 64 + m * 16 + lr) * 32 + lg * 8];
    }
  };
  auto rdB = [&](bf16x8 (&bb)[2][2], int t, int ch) { // 4 ds_read_b128
#pragma unroll
    for (int kh = 0; kh < 2; kh++) {
      const u16* p = lB + ((t & 1) * 2 + kh) * 8192;
#pragma unroll
      for (int n = 0; n < 2; n++)
        bb[n][kh] = *(const bf16x8*)&p[(wn * 64 + ch * 32 + n * 16 + lr) * 32 + lg * 8];
    }
  };

  // prologue: tile 0 fully staged; retire A0,A1,B0 (B1 stays in flight)
  stageA(0, 0); stageA(0, 1); stageB(0, 0); stageB(0, 1);
  waitv<2>();
  barrier_f();

  for (int t = 0; t < NT; t++) {
    bool st = (t + 1 < NT);
    // ---- p1: quadrant (rh0, ch0) ----
    rdA(t, 0); rdB(bF0, t, 0);
    if (st) { stageA(t + 1, 0); stageA(t + 1, 1); }
    barrier_f(); lgkm0();
    __builtin_amdgcn_s_setprio(1);
#pragma unroll
    for (int m = 0; m < 4; m++)
#pragma unroll
      for (int n = 0; n < 2; n++)
#pragma unroll
        for (int kh = 0; kh < 2; kh++)
          acc[m][n] = __builtin_amdgcn_mfma_f32_16x16x32_bf16(bF0[n][kh], aF[m][kh], acc[m][n], 0, 0, 0);
    __builtin_amdgcn_s_setprio(0);
    if (st) waitv<4>(); else waitv<0>();  // retire B1(t)
    barrier_f();
    // ---- p2: quadrant (rh0, ch1) ----
    rdB(bF1, t, 1);
    if (st) stageB(t + 1, 0);
    barrier_f(); lgkm0();
    __builtin_amdgcn_s_setprio(1);
#pragma unroll
    for (int m = 0; m < 4; m++)
#pragma unroll
      for (int n = 0; n < 2; n++)
#pragma unroll
        for (int kh = 0; kh < 2; kh++)
          acc[m][2 + n] = __builtin_amdgcn_mfma_f32_16x16x32_bf16(bF1[n][kh], aF[m][kh], acc[m][2 + n], 0, 0, 0);
    __builtin_amdgcn_s_setprio(0);
    barrier_f();
    // ---- p3: quadrant (rh1, ch0) ----
    rdA(t, 1);
    if (st) stageB(t + 1, 1);
    barrier_f(); lgkm0();
    __builtin_amdgcn_s_setprio(1);
#pragma unroll
    for (int m = 0; m < 4; m++)
#pragma unroll
      for (int n = 0; n < 2; n++)
#pragma unroll
        for (int kh = 0; kh < 2; kh++)
          acc[4 + m][n] = __builtin_amdgcn_mfma_f32_16x16x32_bf16(bF0[n][kh], aF[m][kh], acc[4 + m][n], 0, 0, 0);
    __builtin_amdgcn_s_setprio(0);
    barrier_f();
    // ---- p4: quadrant (rh1, ch1) ----
    barrier_f(); lgkm0();
    __builtin_amdgcn_s_setprio(1);
#pragma unroll
    for (int m = 0; m < 4; m++)
#pragma unroll
      for (int n = 0; n < 2; n++)
#pragma unroll
        for (int kh = 0; kh < 2; kh++)
          acc[4 + m][2 + n] = __builtin_amdgcn_mfma_f32_16x16x32_bf16(bF1[n][kh], aF[m][kh], acc[4 + m][2 + n], 0, 0, 0);
    __builtin_amdgcn_s_setprio(0);
    if (st) waitv<2>();                   // retire A0,A1,B0 of t+1
    barrier_f();
  }

  // epilogue: lane holds C rows (wm*128 + mi*16 + lr), col quad (wn*64 + ni*16 + lg*4)
#pragma unroll
  for (int mi = 0; mi < 8; mi++) {
    int grow = rowBase + wm * 128 + mi * 16 + lr;
#pragma unroll
    for (int ni = 0; ni < 4; ni++) {
      int gcol = colBase + wn * 64 + ni * 16 + lg * 4;
      f32x4 v4 = acc[mi][ni];
      if constexpr (MODE == 0) {
        if (gcol < 2048) {                // q (scaled) / k -> row-major
          bool isq = gcol < 1024;
          u16* dst = isq ? o0 : o1;
          s16x4 o4;
#pragma unroll
          for (int j = 0; j < 4; j++)
            o4[j] = (short)f2bf(isq ? v4[j] * 0.18033688011112042f : v4[j]);
          *(s16x4*)&dst[(size_t)grow * 1024 + (gcol & 1023)] = o4;
        } else {                          // v -> transposed direct
          int c = gcol - 2048;            // h*64+d; quad stays in one head
          int bb = grow >> 11, ss = grow & 2047;
          size_t vbase = ((size_t)bb * 1024 + c) * 2048 + ss;
#pragma unroll
          for (int j = 0; j < 4; j++)
            o2[vbase + (size_t)j * 2048] = f2bf(v4[j]);
        }
      } else {                            // MODE 2: gelu(C + bias)
        float4 bq = *(const float4*)&bias[gcol];
        s16x4 o4;
#pragma unroll
        for (int j = 0; j < 4; j++) {
          float g = v4[j] + ((const float*)&bq)[j];
          float e = __builtin_amdgcn_exp2f(2.302208198f * (g + 0.044715f * g * g * g));
          o4[j] = (short)f2bf(g - g * __builtin_amdgcn_rcpf(1.0f + e));
        }
        *(s16x4*)&o0[(size_t)grow * N + gcol] = o4;
      }
    }
  }
}

// ---- Flash attention: block = (b, h, 128 q-rows); 4 waves x 32 rows -------
// R15 version (measured best): exp2-domain scores, NO max tracking.
__global__ __launch_bounds__(256) void attn_kernel(const u16* __restrict__ q,
                                                   const u16* __restrict__ k,
                                                   const u16* __restrict__ vt,
                                                   u16* __restrict__ o) {
  __shared__ __align__(16) u16 lK[64 * 64];
  __shared__ __align__(16) u16 lV[64 * 64];
  __shared__ __align__(16) u16 lP[4 * 2 * 16 * 64];
  const int S = 2048, E = 1024;
  int qt = blockIdx.x, h = blockIdx.y, b = blockIdx.z;
  int tid = threadIdx.x, wid = tid >> 6, lane = tid & 63;
  int lr = lane & 15, lg = lane >> 4;
  u16* lPw = &lP[wid * 2048];

  const u16* qp = q + ((size_t)b * S + qt * 128 + wid * 32) * E + h * 64;
  const u16* kp = k + (size_t)b * S * E + h * 64;
  const u16* vp = vt + ((size_t)(b * 16 + h) * 64) * S;

  bf16x8 aQ[2][2];
#pragma unroll
  for (int m = 0; m < 2; m++)
#pragma unroll
    for (int kk = 0; kk < 2; kk++)
      aQ[m][kk] = *(const bf16x8*)(qp + (size_t)(m * 16 + lr) * E + kk * 32 + lg * 8);

  bf16x8 onesv;
#pragma unroll
  for (int i = 0; i < 8; i++) onesv[i] = (short)0x3F80;

  f32x4 accO[2][4], accL[2];
  f32x4 zero = {0.f, 0.f, 0.f, 0.f};
#pragma unroll
  for (int m = 0; m < 2; m++) {
    accL[m] = zero;
#pragma unroll
    for (int nn = 0; nn < 4; nn++) accO[m][nn] = zero;
  }

  int sr_ = tid >> 3, sc_ = (tid & 7) * 8;
  const u16* kps0 = kp + (size_t)sr_ * E + sc_;
  const u16* kps1 = kp + (size_t)(sr_ + 32) * E + sc_;
  const u16* vps0 = vp + (size_t)sr_ * S + sc_;
  const u16* vps1 = vp + (size_t)(sr_ + 32) * S + sc_;

  bf16x8 rk0 = *(const bf16x8*)(kps0);
  bf16x8 rk1 = *(const bf16x8*)(kps1);
  bf16x8 rv0 = *(const bf16x8*)(vps0);
  bf16x8 rv1 = *(const bf16x8*)(vps1);

  for (int kv0 = 0; kv0 < S; kv0 += 64) {
    __syncthreads();
    *(bf16x8*)&lK[swzi(sr_, sc_)] = rk0;
    *(bf16x8*)&lK[swzi(32 + sr_, sc_)] = rk1;
    *(bf16x8*)&lV[swzi(sr_, sc_)] = rv0;
    *(bf16x8*)&lV[swzi(32 + sr_, sc_)] = rv1;
    int nx = kv0 + 64;
    if (nx < S) {
      rk0 = *(const bf16x8*)(kps0 + (size_t)nx * E);
      rk1 = *(const bf16x8*)(kps1 + (size_t)nx * E);
      rv0 = *(const bf16x8*)(vps0 + nx);
      rv1 = *(const bf16x8*)(vps1 + nx);
    }
    __syncthreads();

    f32x4 sc4[2][4];
#pragma unroll
    for (int m = 0; m < 2; m++)
#pragma unroll
      for (int n = 0; n < 4; n++) sc4[m][n] = zero;
#pragma unroll
    for (int n = 0; n < 4; n++) {
      bf16x8 bk0 = *(const bf16x8*)&lK[swzi(n * 16 + lr, lg * 8)];
      bf16x8 bk1 = *(const bf16x8*)&lK[swzi(n * 16 + lr, 32 + lg * 8)];
#pragma unroll
      for (int m = 0; m < 2; m++) {
        sc4[m][n] = __builtin_amdgcn_mfma_f32_16x16x32_bf16(bk0, aQ[m][0], sc4[m][n], 0, 0, 0);
        sc4[m][n] = __builtin_amdgcn_mfma_f32_16x16x32_bf16(bk1, aQ[m][1], sc4[m][n], 0, 0, 0);
      }
    }

#pragma unroll
    for (int m = 0; m < 2; m++)
#pragma unroll
      for (int n = 0; n < 4; n++) {
        s16x4 pq;
#pragma unroll
        for (int j = 0; j < 4; j++)
          pq[j] = (short)f2bf_tr(__builtin_amdgcn_exp2f(sc4[m][n][j]));
        *(s16x4*)&lPw[m * 1024 + swzi(lr, n * 16 + lg * 4)] = pq;
      }

#pragma unroll
    for (int kk = 0; kk < 2; kk++) {
      bf16x8 ap[2];
#pragma unroll
      for (int m = 0; m < 2; m++)
        ap[m] = *(const bf16x8*)&lPw[m * 1024 + swzi(lr, kk * 32 + lg * 8)];
#pragma unroll
      for (int m = 0; m < 2; m++)
        accL[m] = __builtin_amdgcn_mfma_f32_16x16x32_bf16(onesv, ap[m], accL[m], 0, 0, 0);
#pragma unroll
      for (int nn = 0; nn < 4; nn++) {
        bf16x8 bv = *(const bf16x8*)&lV[swzi(nn * 16 + lr, kk * 32 + lg * 8)];
#pragma unroll
        for (int m = 0; m < 2; m++)
          accO[m][nn] = __builtin_amdgcn_mfma_f32_16x16x32_bf16(bv, ap[m], accO[m][nn], 0, 0, 0);
      }
    }
  }

#pragma unroll
  for (int m = 0; m < 2; m++) {
    float inv = 1.0f / accL[m][0];
    int srow = qt * 128 + wid * 32 + m * 16 + lr;
#pragma unroll
    for (int nn = 0; nn < 4; nn++) {
      s16x4 o4;
#pragma unroll
      for (int j = 0; j < 4; j++) o4[j] = (short)f2bf(accO[m][nn][j] * inv);
      *(s16x4*)&o[((size_t)b * S + srow) * E + h * 64 + nn * 16 + lg * 4] = o4;
    }
  }
}

// ---------------------------------------------------------------------------
extern "C" void kernel_launch(void* const* d_in, const int* in_sizes, int n_in,
                              void* d_out, int out_size, void* d_ws, size_t ws_size,
                              hipStream_t stream) {
  (void)in_sizes; (void)n_in; (void)out_size; (void)ws_size;
  const float* x     = (const float*)d_in[0];
  const float* w_qkv = (const float*)d_in[1];
  const float* w_fc  = (const float*)d_in[2];
  const float* w1    = (const float*)d_in[3];
  const float* b1    = (const float*)d_in[4];
  const float* w2    = (const float*)d_in[5];
  const float* b2    = (const float*)d_in[6];
  float* out = (float*)d_out;
  char* ws = (char*)d_ws;

  // workspace layout (80 MB total)
  u16* wqkvT = (u16*)(ws);                  // [3072][1024] 6 MB
  u16* wfcT  = (u16*)(ws + 6291456);        // [1024][1024] 2 MB
  u16* w1T   = (u16*)(ws + 8388608);        // [4096][1024] 8 MB
  u16* w2T   = (u16*)(ws + 16777216);       // [1024][4096] 8 MB
  u16* hbuf  = (u16*)(ws + 25165824);       // h1 -> attnout -> h2, 8 MB
  u16* qbuf  = (u16*)(ws + 33554432);       // 8 MB
  u16* kbuf  = (u16*)(ws + 41943040);       // 8 MB
  u16* vtbuf = (u16*)(ws + 58720256);       // 8 MB (written directly by qkv)
  float* x2  = (float*)(ws + 67108864);     // 16 MB f32
  u16* act   = qbuf;                        // [4096][4096] 32 MB over q..vt (dead)

  wcastT<<<dim3(96, 32), 256, 0, stream>>>(w_qkv, wqkvT, 1024, 3072);
  wcastT<<<dim3(32, 32), 256, 0, stream>>>(w_fc, wfcT, 1024, 1024);
  wcastT<<<dim3(128, 32), 256, 0, stream>>>(w1, w1T, 1024, 4096);
  wcastT<<<dim3(32, 128), 256, 0, stream>>>(w2, w2T, 4096, 1024);

  ln_kernel<<<4096, 256, 0, stream>>>(x, hbuf);
  gemm256p<0><<<dim3(12, 16), 512, 0, stream>>>(hbuf, wqkvT, 3072,
                                                nullptr, qbuf, kbuf, vtbuf);
  attn_kernel<<<dim3(16, 16, 2), 256, 0, stream>>>(qbuf, kbuf, vtbuf, hbuf);
  gemm_bt<1, 64, 64><<<dim3(8, 64), 256, 0, stream>>>(hbuf, wfcT, 1024, 1024,
                                                      x, nullptr, x2);
  ln_kernel<<<4096, 256, 0, stream>>>(x2, hbuf);
  gemm256p<2><<<dim3(16, 16), 512, 0, stream>>>(hbuf, w1T, 4096,
                                                b1, act, nullptr, nullptr);
  gemm_bt<3, 64, 64><<<dim3(8, 64), 256, 0, stream>>>(act, w2T, 1024, 4096,
                                                      x2, b2, out);
}

// Round 21
// 235.493 us; speedup vs baseline: 1.0362x; 1.0362x over previous
//
#include <hip/hip_runtime.h>

typedef unsigned short u16;
typedef __attribute__((ext_vector_type(8))) short bf16x8;   // 8 x bf16 (4 VGPRs)
typedef __attribute__((ext_vector_type(4))) short s16x4;
typedef __attribute__((ext_vector_type(4))) float f32x4;

#define DEV __device__ __forceinline__

DEV u16 f2bf(float f) {                       // fp32 -> bf16 bits, RNE
  union { float f; unsigned u; } v; v.f = f;
  unsigned r = v.u + 0x7fffu + ((v.u >> 16) & 1u);
  return (u16)(r >> 16);
}
DEV u16 f2bf_tr(float f) {                    // truncating (P only; bias cancels in O/l)
  union { float f; unsigned u; } v; v.f = f;
  return (u16)(v.u >> 16);
}

// XOR bank-swizzle for a 64-col bf16 LDS tile (u16 index units).
DEV int swzi(int row, int col) { return row * 64 + (col ^ ((row & 7) << 3)); }

// async global->LDS, 16B per lane. LDS dest is wave-uniform base; HW adds lane*16.
DEV void gl16(const u16* g, u16* l) {
  __builtin_amdgcn_global_load_lds((const __attribute__((address_space(1))) void*)g,
                                   (__attribute__((address_space(3))) void*)l, 16, 0, 0);
}

template <int N> DEV void waitv() {           // counted vmcnt (compile-time imm)
  asm volatile("s_waitcnt vmcnt(%0)" :: "n"(N) : "memory");
}
DEV void barrier_f() {
  __builtin_amdgcn_s_barrier();
  asm volatile("" ::: "memory");
}
DEV void lgkm0() { asm volatile("s_waitcnt lgkmcnt(0)" ::: "memory"); }

// ---- weight cast + transpose: w[K][N] f32 -> wt[N][K] bf16 ----------------
__global__ __launch_bounds__(256) void wcastT(const float* __restrict__ w,
                                              u16* __restrict__ wt, int K, int N) {
  __shared__ float t[32][33];
  int n0 = blockIdx.x * 32, k0 = blockIdx.y * 32;
  int tx = threadIdx.x & 31, ty = threadIdx.x >> 5;
#pragma unroll
  for (int i = 0; i < 32; i += 8)
    t[ty + i][tx] = w[(size_t)(k0 + ty + i) * N + n0 + tx];
  __syncthreads();
#pragma unroll
  for (int i = 0; i < 32; i += 8)
    wt[(size_t)(n0 + ty + i) * K + k0 + tx] = f2bf(t[tx][ty + i]);
}

// ---- LayerNorm (1024 cols, no affine) f32 -> bf16 -------------------------
__global__ __launch_bounds__(256) void ln_kernel(const float* __restrict__ x,
                                                 u16* __restrict__ out) {
  int row = blockIdx.x, tid = threadIdx.x;
  const float4* xr = (const float4*)(x + (size_t)row * 1024);
  float4 f = xr[tid];
  float s = f.x + f.y + f.z + f.w;
  float s2 = f.x * f.x + f.y * f.y + f.z * f.z + f.w * f.w;
#pragma unroll
  for (int o = 1; o < 64; o <<= 1) { s += __shfl_xor(s, o); s2 += __shfl_xor(s2, o); }
  __shared__ float red[2][4];
  int wid = tid >> 6;
  if ((tid & 63) == 0) { red[0][wid] = s; red[1][wid] = s2; }
  __syncthreads();
  float tot  = red[0][0] + red[0][1] + red[0][2] + red[0][3];
  float tot2 = red[1][0] + red[1][1] + red[1][2] + red[1][3];
  float mu = tot * (1.0f / 1024.0f);
  float var = tot2 * (1.0f / 1024.0f) - mu * mu;
  float rstd = rsqrtf(var + 1e-5f);
  s16x4 o4;
  o4[0] = (short)f2bf((f.x - mu) * rstd);
  o4[1] = (short)f2bf((f.y - mu) * rstd);
  o4[2] = (short)f2bf((f.z - mu) * rstd);
  o4[3] = (short)f2bf((f.w - mu) * rstd);
  *(s16x4*)(out + (size_t)row * 1024 + tid * 4) = o4;
}

// ---- GEMM: C[M,N] = A[M,K](bf16) * Bt[N,K]^T(bf16), fused epilogues -------
// R15/R17-proven structure (session best). qkv BM=128/BK=32; fc/mlp2 64/64.
// MODE 0: qkv split -> q(o0, pre-scaled 0.125*log2e), k(o1), V^T direct (o2)
// MODE 1: outF = resid + C (f32)        MODE 3: outF = resid + bias + C
template <int MODE, int BM, int BK>
__global__ __launch_bounds__(256) void gemm_bt(
    const u16* __restrict__ A, const u16* __restrict__ Bt, int N, int K,
    const float* __restrict__ resid, const float* __restrict__ bias,
    float* __restrict__ outF, u16* __restrict__ o0, u16* __restrict__ o1,
    u16* __restrict__ o2) {
  constexpr int MR = BM / 32;
  constexpr int KH = BK / 32;
  constexpr int LDEPTH = KH * (BM / 64 + 2);
  constexpr int ACH = BM * 32, BCH = 128 * 32;
  __shared__ __align__(16) u16 lA[2 * KH * ACH];
  __shared__ __align__(16) u16 lB[2 * KH * BCH];
  int tid = threadIdx.x;
  int lane = tid & 63, wid = tid >> 6;
  int lr = lane & 15, lg = lane >> 4;

  int gx = gridDim.x;
  int nwg = gx * gridDim.y;
  int bid = blockIdx.y * gx + blockIdx.x;
  int swz = (bid & 7) * (nwg >> 3) + (bid >> 3);
  int rowBase = (swz / gx) * BM, colBase = (swz % gx) * 128;
  int wr = (wid >> 1) * (MR * 16), wc = (wid & 1) * 64;

  int srow = wid * 16 + (lane >> 2);
  int scol = (lane & 3) * 8;
  const u16* gA = A + (size_t)(rowBase + srow) * K + scol;
  const u16* gB = Bt + (size_t)(colBase + srow) * K + scol;
  u16* lAb = &lA[wid * 16 * 32];
  u16* lBb = &lB[wid * 16 * 32];

  auto stage = [&](int t, int buf) {
    int k0 = t * BK;
#pragma unroll
    for (int kk = 0; kk < KH; kk++) {
      u16* dA = lAb + buf * KH * ACH + kk * ACH;
      u16* dB = lBb + buf * KH * BCH + kk * BCH;
      int koff = k0 + kk * 32;
#pragma unroll
      for (int c = 0; c < BM / 64; c++)
        gl16(gA + (size_t)c * 64 * K + koff, dA + c * 64 * 32);
#pragma unroll
      for (int c = 0; c < 2; c++)
        gl16(gB + (size_t)c * 64 * K + koff, dB + c * 64 * 32);
    }
  };

  f32x4 acc[MR][4];
  f32x4 zero = {0.f, 0.f, 0.f, 0.f};
#pragma unroll
  for (int m = 0; m < MR; m++)
#pragma unroll
    for (int n = 0; n < 4; n++) acc[m][n] = zero;

  stage(0, 0);

  int nt = K / BK;
  for (int t = 0; t < nt; t++) {
    int cur = t & 1;
    if (t + 1 < nt) {
      stage(t + 1, cur ^ 1);
      waitv<LDEPTH>();
    } else {
      waitv<0>();
    }
    barrier_f();

    const u16* cA = &lA[cur * KH * ACH];
    const u16* cB = &lB[cur * KH * BCH];
#pragma unroll
    for (int kk = 0; kk < KH; kk++) {
      bf16x8 af[MR], bfv[4];
#pragma unroll
      for (int m = 0; m < MR; m++)
        af[m] = *(const bf16x8*)&cA[kk * ACH + (wr + m * 16 + lr) * 32 + lg * 8];
#pragma unroll
      for (int n = 0; n < 4; n++)
        bfv[n] = *(const bf16x8*)&cB[kk * BCH + (wc + n * 16 + lr) * 32 + lg * 8];
#pragma unroll
      for (int m = 0; m < MR; m++)
#pragma unroll
        for (int n = 0; n < 4; n++)
          acc[m][n] = __builtin_amdgcn_mfma_f32_16x16x32_bf16(bfv[n], af[m], acc[m][n], 0, 0, 0);
    }
    barrier_f();
  }

#pragma unroll
  for (int m = 0; m < MR; m++) {
    int grow = rowBase + wr + m * 16 + lr;
#pragma unroll
    for (int n = 0; n < 4; n++) {
      int gcol = colBase + wc + n * 16 + lg * 4;
      f32x4 v4 = acc[m][n];
      if constexpr (MODE == 0) {
        if (gcol < 2048) {
          bool isq = gcol < 1024;
          u16* dst = isq ? o0 : o1;
          s16x4 o4;
#pragma unroll
          for (int j = 0; j < 4; j++)
            o4[j] = (short)f2bf(isq ? v4[j] * 0.18033688011112042f : v4[j]);
          *(s16x4*)&dst[(size_t)grow * 1024 + (gcol & 1023)] = o4;
        } else {
          int c = gcol - 2048;
          int bb = grow >> 11, ss = grow & 2047;
          size_t vbase = ((size_t)bb * 1024 + c) * 2048 + ss;
#pragma unroll
          for (int j = 0; j < 4; j++)
            o2[vbase + (size_t)j * 2048] = f2bf(v4[j]);
        }
      } else if constexpr (MODE == 1) {
        size_t idx = (size_t)grow * N + gcol;
        float4 r = *(const float4*)&resid[idx];
        float4 ov = {r.x + v4[0], r.y + v4[1], r.z + v4[2], r.w + v4[3]};
        *(float4*)&outF[idx] = ov;
      } else {
        size_t idx = (size_t)grow * N + gcol;
        float4 r = *(const float4*)&resid[idx];
        float4 bq = *(const float4*)&bias[gcol];
        float4 ov = {r.x + bq.x + v4[0], r.y + bq.y + v4[1],
                     r.z + bq.z + v4[2], r.w + bq.w + v4[3]};
        *(float4*)&outF[idx] = ov;
      }
    }
  }
}

// ---- mlp1: 256x256 4-phase pipelined GEMM (R18 measured best) -------------
// M=N=4096, K=1024, grid 256 = machine-filling. 8 waves (2Mx4N), wave tile
// 128x64. K-tile 64 as two [256][32] u16 chunks/operand (64B stride =
// conflict-free b128 reads; gl16 dest linear). 4 phases/tile = one
// C-quadrant x K=64 = 16 MFMA between barriers + setprio. Counted waits:
// vmcnt<2> in p4 (retires t+1's A0,A1,B0), vmcnt<4> in p1 (retires t+1's
// B1); each validated by that phase's closing barrier before the consuming
// phase's pre-barrier ds_reads. WAR: stage of t+1 into buf (t+1)&1 follows
// t-1's final closing barrier.
__global__ __launch_bounds__(512, 1) void gemm256p(
    const u16* __restrict__ A, const u16* __restrict__ Bt,
    const float* __restrict__ bias, u16* __restrict__ o0) {
  constexpr int K = 1024, N = 4096, NT = 16;
  __shared__ __align__(16) u16 lA[2 * 2 * 256 * 32];  // [buf][kh][256][32] 64KB
  __shared__ __align__(16) u16 lB[2 * 2 * 256 * 32];  // 64KB
  int tid = threadIdx.x;
  int lane = tid & 63, wid = tid >> 6;
  int lr = lane & 15, lg = lane >> 4;
  int wm = wid >> 2, wn = wid & 3;                    // 2M x 4N wave grid

  int gx = gridDim.x;                                 // 16
  int nwg = gx * gridDim.y;                           // 256 (%8==0)
  int bid = blockIdx.y * gx + blockIdx.x;
  int swz = (bid & 7) * (nwg >> 3) + (bid >> 3);
  int rowBase = (swz / gx) * 256, colBase = (swz % gx) * 256;

  int sr0 = tid >> 2, sc = (tid & 3) * 8;             // staging: 128 rows/round
  const u16* gA = A + (size_t)(rowBase + sr0) * K + sc;
  const u16* gB = Bt + (size_t)(colBase + sr0) * K + sc;
  u16* lAw = lA + wid * 512;                          // wave-uniform base
  u16* lBw = lB + wid * 512;

  auto stageA = [&](int t, int kh) {                  // 2 gl16 / thread
    int koff = t * 64 + kh * 32;
    u16* d = lAw + ((t & 1) * 2 + kh) * 8192;
    gl16(gA + koff, d);
    gl16(gA + (size_t)128 * K + koff, d + 4096);
  };
  auto stageB = [&](int t, int kh) {
    int koff = t * 64 + kh * 32;
    u16* d = lBw + ((t & 1) * 2 + kh) * 8192;
    gl16(gB + koff, d);
    gl16(gB + (size_t)128 * K + koff, d + 4096);
  };

  f32x4 acc[8][4];
  f32x4 zero = {0.f, 0.f, 0.f, 0.f};
#pragma unroll
  for (int m = 0; m < 8; m++)
#pragma unroll
    for (int n = 0; n < 4; n++) acc[m][n] = zero;

  bf16x8 aF[4][2], bF0[2][2], bF1[2][2];              // operand frags

  auto rdA = [&](int t, int rh) {                     // 8 ds_read_b128
#pragma unroll
    for (int kh = 0; kh < 2; kh++) {
      const u16* p = lA + ((t & 1) * 2 + kh) * 8192;
#pragma unroll
      for (int m = 0; m < 4; m++)
        aF[m][kh] = *(const bf16x8*)&p[(wm * 128 + rh * 64 + m * 16 + lr) * 32 + lg * 8];
    }
  };
  auto rdB = [&](bf16x8 (&bb)[2][2], int t, int ch) { // 4 ds_read_b128
#pragma unroll
    for (int kh = 0; kh < 2; kh++) {
      const u16* p = lB + ((t & 1) * 2 + kh) * 8192;
#pragma unroll
      for (int n = 0; n < 2; n++)
        bb[n][kh] = *(const bf16x8*)&p[(wn * 64 + ch * 32 + n * 16 + lr) * 32 + lg * 8];
    }
  };

  // prologue: tile 0 fully staged; retire A0,A1,B0 (B1 stays in flight)
  stageA(0, 0); stageA(0, 1); stageB(0, 0); stageB(0, 1);
  waitv<2>();
  barrier_f();

  for (int t = 0; t < NT; t++) {
    bool st = (t + 1 < NT);
    // ---- p1: quadrant (rh0, ch0) ----
    rdA(t, 0); rdB(bF0, t, 0);
    if (st) { stageA(t + 1, 0); stageA(t + 1, 1); }
    barrier_f(); lgkm0();
    __builtin_amdgcn_s_setprio(1);
#pragma unroll
    for (int m = 0; m < 4; m++)
#pragma unroll
      for (int n = 0; n < 2; n++)
#pragma unroll
        for (int kh = 0; kh < 2; kh++)
          acc[m][n] = __builtin_amdgcn_mfma_f32_16x16x32_bf16(bF0[n][kh], aF[m][kh], acc[m][n], 0, 0, 0);
    __builtin_amdgcn_s_setprio(0);
    if (st) waitv<4>(); else waitv<0>();  // retire B1(t)
    barrier_f();
    // ---- p2: quadrant (rh0, ch1) ----
    rdB(bF1, t, 1);
    if (st) stageB(t + 1, 0);
    barrier_f(); lgkm0();
    __builtin_amdgcn_s_setprio(1);
#pragma unroll
    for (int m = 0; m < 4; m++)
#pragma unroll
      for (int n = 0; n < 2; n++)
#pragma unroll
        for (int kh = 0; kh < 2; kh++)
          acc[m][2 + n] = __builtin_amdgcn_mfma_f32_16x16x32_bf16(bF1[n][kh], aF[m][kh], acc[m][2 + n], 0, 0, 0);
    __builtin_amdgcn_s_setprio(0);
    barrier_f();
    // ---- p3: quadrant (rh1, ch0) ----
    rdA(t, 1);
    if (st) stageB(t + 1, 1);
    barrier_f(); lgkm0();
    __builtin_amdgcn_s_setprio(1);
#pragma unroll
    for (int m = 0; m < 4; m++)
#pragma unroll
      for (int n = 0; n < 2; n++)
#pragma unroll
        for (int kh = 0; kh < 2; kh++)
          acc[4 + m][n] = __builtin_amdgcn_mfma_f32_16x16x32_bf16(bF0[n][kh], aF[m][kh], acc[4 + m][n], 0, 0, 0);
    __builtin_amdgcn_s_setprio(0);
    barrier_f();
    // ---- p4: quadrant (rh1, ch1) ----
    barrier_f(); lgkm0();
    __builtin_amdgcn_s_setprio(1);
#pragma unroll
    for (int m = 0; m < 4; m++)
#pragma unroll
      for (int n = 0; n < 2; n++)
#pragma unroll
        for (int kh = 0; kh < 2; kh++)
          acc[4 + m][2 + n] = __builtin_amdgcn_mfma_f32_16x16x32_bf16(bF1[n][kh], aF[m][kh], acc[4 + m][2 + n], 0, 0, 0);
    __builtin_amdgcn_s_setprio(0);
    if (st) waitv<2>();                   // retire A0,A1,B0 of t+1
    barrier_f();
  }

  // epilogue: lane holds C rows (wm*128 + mi*16 + lr), col quad (wn*64 + ni*16 + lg*4)
#pragma unroll
  for (int mi = 0; mi < 8; mi++) {
    int grow = rowBase + wm * 128 + mi * 16 + lr;
#pragma unroll
    for (int ni = 0; ni < 4; ni++) {
      int gcol = colBase + wn * 64 + ni * 16 + lg * 4;
      f32x4 v4 = acc[mi][ni];
      float4 bq = *(const float4*)&bias[gcol];
      s16x4 o4;
#pragma unroll
      for (int j = 0; j < 4; j++) {
        float g = v4[j] + ((const float*)&bq)[j];
        float e = __builtin_amdgcn_exp2f(2.302208198f * (g + 0.044715f * g * g * g));
        o4[j] = (short)f2bf(g - g * __builtin_amdgcn_rcpf(1.0f + e));
      }
      *(s16x4*)&o0[(size_t)grow * N + gcol] = o4;
    }
  }
}

// ---- Flash attention: block = (b, h, 128 q-rows); 4 waves x 32 rows -------
// R15 version (measured best): exp2-domain scores, NO max tracking.
__global__ __launch_bounds__(256) void attn_kernel(const u16* __restrict__ q,
                                                   const u16* __restrict__ k,
                                                   const u16* __restrict__ vt,
                                                   u16* __restrict__ o) {
  __shared__ __align__(16) u16 lK[64 * 64];
  __shared__ __align__(16) u16 lV[64 * 64];
  __shared__ __align__(16) u16 lP[4 * 2 * 16 * 64];
  const int S = 2048, E = 1024;
  int qt = blockIdx.x, h = blockIdx.y, b = blockIdx.z;
  int tid = threadIdx.x, wid = tid >> 6, lane = tid & 63;
  int lr = lane & 15, lg = lane >> 4;
  u16* lPw = &lP[wid * 2048];

  const u16* qp = q + ((size_t)b * S + qt * 128 + wid * 32) * E + h * 64;
  const u16* kp = k + (size_t)b * S * E + h * 64;
  const u16* vp = vt + ((size_t)(b * 16 + h) * 64) * S;

  bf16x8 aQ[2][2];
#pragma unroll
  for (int m = 0; m < 2; m++)
#pragma unroll
    for (int kk = 0; kk < 2; kk++)
      aQ[m][kk] = *(const bf16x8*)(qp + (size_t)(m * 16 + lr) * E + kk * 32 + lg * 8);

  bf16x8 onesv;
#pragma unroll
  for (int i = 0; i < 8; i++) onesv[i] = (short)0x3F80;

  f32x4 accO[2][4], accL[2];
  f32x4 zero = {0.f, 0.f, 0.f, 0.f};
#pragma unroll
  for (int m = 0; m < 2; m++) {
    accL[m] = zero;
#pragma unroll
    for (int nn = 0; nn < 4; nn++) accO[m][nn] = zero;
  }

  int sr_ = tid >> 3, sc_ = (tid & 7) * 8;
  const u16* kps0 = kp + (size_t)sr_ * E + sc_;
  const u16* kps1 = kp + (size_t)(sr_ + 32) * E + sc_;
  const u16* vps0 = vp + (size_t)sr_ * S + sc_;
  const u16* vps1 = vp + (size_t)(sr_ + 32) * S + sc_;

  bf16x8 rk0 = *(const bf16x8*)(kps0);
  bf16x8 rk1 = *(const bf16x8*)(kps1);
  bf16x8 rv0 = *(const bf16x8*)(vps0);
  bf16x8 rv1 = *(const bf16x8*)(vps1);

  for (int kv0 = 0; kv0 < S; kv0 += 64) {
    __syncthreads();
    *(bf16x8*)&lK[swzi(sr_, sc_)] = rk0;
    *(bf16x8*)&lK[swzi(32 + sr_, sc_)] = rk1;
    *(bf16x8*)&lV[swzi(sr_, sc_)] = rv0;
    *(bf16x8*)&lV[swzi(32 + sr_, sc_)] = rv1;
    int nx = kv0 + 64;
    if (nx < S) {
      rk0 = *(const bf16x8*)(kps0 + (size_t)nx * E);
      rk1 = *(const bf16x8*)(kps1 + (size_t)nx * E);
      rv0 = *(const bf16x8*)(vps0 + nx);
      rv1 = *(const bf16x8*)(vps1 + nx);
    }
    __syncthreads();

    f32x4 sc4[2][4];
#pragma unroll
    for (int m = 0; m < 2; m++)
#pragma unroll
      for (int n = 0; n < 4; n++) sc4[m][n] = zero;
#pragma unroll
    for (int n = 0; n < 4; n++) {
      bf16x8 bk0 = *(const bf16x8*)&lK[swzi(n * 16 + lr, lg * 8)];
      bf16x8 bk1 = *(const bf16x8*)&lK[swzi(n * 16 + lr, 32 + lg * 8)];
#pragma unroll
      for (int m = 0; m < 2; m++) {
        sc4[m][n] = __builtin_amdgcn_mfma_f32_16x16x32_bf16(bk0, aQ[m][0], sc4[m][n], 0, 0, 0);
        sc4[m][n] = __builtin_amdgcn_mfma_f32_16x16x32_bf16(bk1, aQ[m][1], sc4[m][n], 0, 0, 0);
      }
    }

#pragma unroll
    for (int m = 0; m < 2; m++)
#pragma unroll
      for (int n = 0; n < 4; n++) {
        s16x4 pq;
#pragma unroll
        for (int j = 0; j < 4; j++)
          pq[j] = (short)f2bf_tr(__builtin_amdgcn_exp2f(sc4[m][n][j]));
        *(s16x4*)&lPw[m * 1024 + swzi(lr, n * 16 + lg * 4)] = pq;
      }

#pragma unroll
    for (int kk = 0; kk < 2; kk++) {
      bf16x8 ap[2];
#pragma unroll
      for (int m = 0; m < 2; m++)
        ap[m] = *(const bf16x8*)&lPw[m * 1024 + swzi(lr, kk * 32 + lg * 8)];
#pragma unroll
      for (int m = 0; m < 2; m++)
        accL[m] = __builtin_amdgcn_mfma_f32_16x16x32_bf16(onesv, ap[m], accL[m], 0, 0, 0);
#pragma unroll
      for (int nn = 0; nn < 4; nn++) {
        bf16x8 bv = *(const bf16x8*)&lV[swzi(nn * 16 + lr, kk * 32 + lg * 8)];
#pragma unroll
        for (int m = 0; m < 2; m++)
          accO[m][nn] = __builtin_amdgcn_mfma_f32_16x16x32_bf16(bv, ap[m], accO[m][nn], 0, 0, 0);
      }
    }
  }

#pragma unroll
  for (int m = 0; m < 2; m++) {
    float inv = 1.0f / accL[m][0];
    int srow = qt * 128 + wid * 32 + m * 16 + lr;
#pragma unroll
    for (int nn = 0; nn < 4; nn++) {
      s16x4 o4;
#pragma unroll
      for (int j = 0; j < 4; j++) o4[j] = (short)f2bf(accO[m][nn][j] * inv);
      *(s16x4*)&o[((size_t)b * S + srow) * E + h * 64 + nn * 16 + lg * 4] = o4;
    }
  }
}

// ---------------------------------------------------------------------------
extern "C" void kernel_launch(void* const* d_in, const int* in_sizes, int n_in,
                              void* d_out, int out_size, void* d_ws, size_t ws_size,
                              hipStream_t stream) {
  (void)in_sizes; (void)n_in; (void)out_size; (void)ws_size;
  const float* x     = (const float*)d_in[0];
  const float* w_qkv = (const float*)d_in[1];
  const float* w_fc  = (const float*)d_in[2];
  const float* w1    = (const float*)d_in[3];
  const float* b1    = (const float*)d_in[4];
  const float* w2    = (const float*)d_in[5];
  const float* b2    = (const float*)d_in[6];
  float* out = (float*)d_out;
  char* ws = (char*)d_ws;

  // workspace layout (80 MB total)
  u16* wqkvT = (u16*)(ws);                  // [3072][1024] 6 MB
  u16* wfcT  = (u16*)(ws + 6291456);        // [1024][1024] 2 MB
  u16* w1T   = (u16*)(ws + 8388608);        // [4096][1024] 8 MB
  u16* w2T   = (u16*)(ws + 16777216);       // [1024][4096] 8 MB
  u16* hbuf  = (u16*)(ws + 25165824);       // h1 -> attnout -> h2, 8 MB
  u16* qbuf  = (u16*)(ws + 33554432);       // 8 MB
  u16* kbuf  = (u16*)(ws + 41943040);       // 8 MB
  u16* vtbuf = (u16*)(ws + 58720256);       // 8 MB (written directly by qkv)
  float* x2  = (float*)(ws + 67108864);     // 16 MB f32
  u16* act   = qbuf;                        // [4096][4096] 32 MB over q..vt (dead)

  wcastT<<<dim3(96, 32), 256, 0, stream>>>(w_qkv, wqkvT, 1024, 3072);
  wcastT<<<dim3(32, 32), 256, 0, stream>>>(w_fc, wfcT, 1024, 1024);
  wcastT<<<dim3(128, 32), 256, 0, stream>>>(w1, w1T, 1024, 4096);
  wcastT<<<dim3(32, 128), 256, 0, stream>>>(w2, w2T, 4096, 1024);

  ln_kernel<<<4096, 256, 0, stream>>>(x, hbuf);
  gemm_bt<0, 128, 32><<<dim3(24, 32), 256, 0, stream>>>(hbuf, wqkvT, 3072, 1024,
                                                        nullptr, nullptr, nullptr,
                                                        qbuf, kbuf, vtbuf);
  attn_kernel<<<dim3(16, 16, 2), 256, 0, stream>>>(qbuf, kbuf, vtbuf, hbuf);
  gemm_bt<1, 64, 64><<<dim3(8, 64), 256, 0, stream>>>(hbuf, wfcT, 1024, 1024,
                                                      x, nullptr, x2,
                                                      nullptr, nullptr, nullptr);
  ln_kernel<<<4096, 256, 0, stream>>>(x2, hbuf);
  gemm256p<<<dim3(16, 16), 512, 0, stream>>>(hbuf, w1T, b1, act);
  gemm_bt<3, 64, 64><<<dim3(8, 64), 256, 0, stream>>>(act, w2T, 1024, 4096,
                                                      x2, b2, out,
                                                      nullptr, nullptr, nullptr);
}

// Round 22
// 228.987 us; speedup vs baseline: 1.0656x; 1.0284x over previous
//
#include <hip/hip_runtime.h>

typedef unsigned short u16;
typedef __attribute__((ext_vector_type(8))) short bf16x8;   // 8 x bf16 (4 VGPRs)
typedef __attribute__((ext_vector_type(4))) short s16x4;
typedef __attribute__((ext_vector_type(4))) float f32x4;

#define DEV __device__ __forceinline__

DEV u16 f2bf(float f) {                       // fp32 -> bf16 bits, RNE
  union { float f; unsigned u; } v; v.f = f;
  unsigned r = v.u + 0x7fffu + ((v.u >> 16) & 1u);
  return (u16)(r >> 16);
}
DEV u16 f2bf_tr(float f) {                    // truncating (P only; bias cancels in O/l)
  union { float f; unsigned u; } v; v.f = f;
  return (u16)(v.u >> 16);
}

// XOR bank-swizzle for a 64-col bf16 LDS tile (u16 index units).
DEV int swzi(int row, int col) { return row * 64 + (col ^ ((row & 7) << 3)); }

// async global->LDS, 16B per lane. LDS dest is wave-uniform base; HW adds lane*16.
DEV void gl16(const u16* g, u16* l) {
  __builtin_amdgcn_global_load_lds((const __attribute__((address_space(1))) void*)g,
                                   (__attribute__((address_space(3))) void*)l, 16, 0, 0);
}

template <int N> DEV void waitv() {           // counted vmcnt (compile-time imm)
  asm volatile("s_waitcnt vmcnt(%0)" :: "n"(N) : "memory");
}
DEV void barrier_f() {
  __builtin_amdgcn_s_barrier();
  asm volatile("" ::: "memory");
}
DEV void lgkm0() { asm volatile("s_waitcnt lgkmcnt(0)" ::: "memory"); }

// ---- fused weight cast+transpose for ALL four weights: one dispatch -------
// segments: [0,3072) w_qkv 1024x3072; [3072,4096) w_fc 1024x1024;
//           [4096,8192) w1 1024x4096; [8192,12288) w2 4096x1024.
__global__ __launch_bounds__(256) void wcastT_all(
    const float* __restrict__ w_qkv, const float* __restrict__ w_fc,
    const float* __restrict__ w1, const float* __restrict__ w2,
    u16* __restrict__ wqkvT, u16* __restrict__ wfcT,
    u16* __restrict__ w1T, u16* __restrict__ w2T) {
  int bid = blockIdx.x;
  const float* w; u16* wt; int K, N, nx, t;
  if (bid < 3072)      { w = w_qkv; wt = wqkvT; K = 1024; N = 3072; nx = 96;  t = bid; }
  else if (bid < 4096) { w = w_fc;  wt = wfcT;  K = 1024; N = 1024; nx = 32;  t = bid - 3072; }
  else if (bid < 8192) { w = w1;    wt = w1T;   K = 1024; N = 4096; nx = 128; t = bid - 4096; }
  else                 { w = w2;    wt = w2T;   K = 4096; N = 1024; nx = 32;  t = bid - 8192; }
  int n0 = (t % nx) * 32, k0 = (t / nx) * 32;

  __shared__ float tl[32][33];
  int tx = threadIdx.x & 31, ty = threadIdx.x >> 5;
#pragma unroll
  for (int i = 0; i < 32; i += 8)
    tl[ty + i][tx] = w[(size_t)(k0 + ty + i) * N + n0 + tx];
  __syncthreads();
#pragma unroll
  for (int i = 0; i < 32; i += 8)
    wt[(size_t)(n0 + ty + i) * K + k0 + tx] = f2bf(tl[tx][ty + i]);
}

// ---- LayerNorm (1024 cols, no affine) f32 -> bf16 -------------------------
__global__ __launch_bounds__(256) void ln_kernel(const float* __restrict__ x,
                                                 u16* __restrict__ out) {
  int row = blockIdx.x, tid = threadIdx.x;
  const float4* xr = (const float4*)(x + (size_t)row * 1024);
  float4 f = xr[tid];
  float s = f.x + f.y + f.z + f.w;
  float s2 = f.x * f.x + f.y * f.y + f.z * f.z + f.w * f.w;
#pragma unroll
  for (int o = 1; o < 64; o <<= 1) { s += __shfl_xor(s, o); s2 += __shfl_xor(s2, o); }
  __shared__ float red[2][4];
  int wid = tid >> 6;
  if ((tid & 63) == 0) { red[0][wid] = s; red[1][wid] = s2; }
  __syncthreads();
  float tot  = red[0][0] + red[0][1] + red[0][2] + red[0][3];
  float tot2 = red[1][0] + red[1][1] + red[1][2] + red[1][3];
  float mu = tot * (1.0f / 1024.0f);
  float var = tot2 * (1.0f / 1024.0f) - mu * mu;
  float rstd = rsqrtf(var + 1e-5f);
  s16x4 o4;
  o4[0] = (short)f2bf((f.x - mu) * rstd);
  o4[1] = (short)f2bf((f.y - mu) * rstd);
  o4[2] = (short)f2bf((f.z - mu) * rstd);
  o4[3] = (short)f2bf((f.w - mu) * rstd);
  *(s16x4*)(out + (size_t)row * 1024 + tid * 4) = o4;
}

// ---- GEMM: C[M,N] = A[M,K](bf16) * Bt[N,K]^T(bf16), fused epilogues -------
// R15/R17-proven structure (session best). qkv BM=128/BK=32; fc/mlp2 64/64.
// MODE 0: qkv split -> q(o0, pre-scaled 0.125*log2e), k(o1), V^T direct (o2)
// MODE 1: outF = resid + C (f32)        MODE 3: outF = resid + bias + C
template <int MODE, int BM, int BK>
__global__ __launch_bounds__(256) void gemm_bt(
    const u16* __restrict__ A, const u16* __restrict__ Bt, int N, int K,
    const float* __restrict__ resid, const float* __restrict__ bias,
    float* __restrict__ outF, u16* __restrict__ o0, u16* __restrict__ o1,
    u16* __restrict__ o2) {
  constexpr int MR = BM / 32;
  constexpr int KH = BK / 32;
  constexpr int LDEPTH = KH * (BM / 64 + 2);
  constexpr int ACH = BM * 32, BCH = 128 * 32;
  __shared__ __align__(16) u16 lA[2 * KH * ACH];
  __shared__ __align__(16) u16 lB[2 * KH * BCH];
  int tid = threadIdx.x;
  int lane = tid & 63, wid = tid >> 6;
  int lr = lane & 15, lg = lane >> 4;

  int gx = gridDim.x;
  int nwg = gx * gridDim.y;
  int bid = blockIdx.y * gx + blockIdx.x;
  int swz = (bid & 7) * (nwg >> 3) + (bid >> 3);
  int rowBase = (swz / gx) * BM, colBase = (swz % gx) * 128;
  int wr = (wid >> 1) * (MR * 16), wc = (wid & 1) * 64;

  int srow = wid * 16 + (lane >> 2);
  int scol = (lane & 3) * 8;
  const u16* gA = A + (size_t)(rowBase + srow) * K + scol;
  const u16* gB = Bt + (size_t)(colBase + srow) * K + scol;
  u16* lAb = &lA[wid * 16 * 32];
  u16* lBb = &lB[wid * 16 * 32];

  auto stage = [&](int t, int buf) {
    int k0 = t * BK;
#pragma unroll
    for (int kk = 0; kk < KH; kk++) {
      u16* dA = lAb + buf * KH * ACH + kk * ACH;
      u16* dB = lBb + buf * KH * BCH + kk * BCH;
      int koff = k0 + kk * 32;
#pragma unroll
      for (int c = 0; c < BM / 64; c++)
        gl16(gA + (size_t)c * 64 * K + koff, dA + c * 64 * 32);
#pragma unroll
      for (int c = 0; c < 2; c++)
        gl16(gB + (size_t)c * 64 * K + koff, dB + c * 64 * 32);
    }
  };

  f32x4 acc[MR][4];
  f32x4 zero = {0.f, 0.f, 0.f, 0.f};
#pragma unroll
  for (int m = 0; m < MR; m++)
#pragma unroll
    for (int n = 0; n < 4; n++) acc[m][n] = zero;

  stage(0, 0);

  int nt = K / BK;
  for (int t = 0; t < nt; t++) {
    int cur = t & 1;
    if (t + 1 < nt) {
      stage(t + 1, cur ^ 1);
      waitv<LDEPTH>();
    } else {
      waitv<0>();
    }
    barrier_f();

    const u16* cA = &lA[cur * KH * ACH];
    const u16* cB = &lB[cur * KH * BCH];
#pragma unroll
    for (int kk = 0; kk < KH; kk++) {
      bf16x8 af[MR], bfv[4];
#pragma unroll
      for (int m = 0; m < MR; m++)
        af[m] = *(const bf16x8*)&cA[kk * ACH + (wr + m * 16 + lr) * 32 + lg * 8];
#pragma unroll
      for (int n = 0; n < 4; n++)
        bfv[n] = *(const bf16x8*)&cB[kk * BCH + (wc + n * 16 + lr) * 32 + lg * 8];
#pragma unroll
      for (int m = 0; m < MR; m++)
#pragma unroll
        for (int n = 0; n < 4; n++)
          acc[m][n] = __builtin_amdgcn_mfma_f32_16x16x32_bf16(bfv[n], af[m], acc[m][n], 0, 0, 0);
    }
    barrier_f();
  }

#pragma unroll
  for (int m = 0; m < MR; m++) {
    int grow = rowBase + wr + m * 16 + lr;
#pragma unroll
    for (int n = 0; n < 4; n++) {
      int gcol = colBase + wc + n * 16 + lg * 4;
      f32x4 v4 = acc[m][n];
      if constexpr (MODE == 0) {
        if (gcol < 2048) {
          bool isq = gcol < 1024;
          u16* dst = isq ? o0 : o1;
          s16x4 o4;
#pragma unroll
          for (int j = 0; j < 4; j++)
            o4[j] = (short)f2bf(isq ? v4[j] * 0.18033688011112042f : v4[j]);
          *(s16x4*)&dst[(size_t)grow * 1024 + (gcol & 1023)] = o4;
        } else {
          int c = gcol - 2048;
          int bb = grow >> 11, ss = grow & 2047;
          size_t vbase = ((size_t)bb * 1024 + c) * 2048 + ss;
#pragma unroll
          for (int j = 0; j < 4; j++)
            o2[vbase + (size_t)j * 2048] = f2bf(v4[j]);
        }
      } else if constexpr (MODE == 1) {
        size_t idx = (size_t)grow * N + gcol;
        float4 r = *(const float4*)&resid[idx];
        float4 ov = {r.x + v4[0], r.y + v4[1], r.z + v4[2], r.w + v4[3]};
        *(float4*)&outF[idx] = ov;
      } else {
        size_t idx = (size_t)grow * N + gcol;
        float4 r = *(const float4*)&resid[idx];
        float4 bq = *(const float4*)&bias[gcol];
        float4 ov = {r.x + bq.x + v4[0], r.y + bq.y + v4[1],
                     r.z + bq.z + v4[2], r.w + bq.w + v4[3]};
        *(float4*)&outF[idx] = ov;
      }
    }
  }
}

// ---- mlp1: 256x256 4-phase pipelined GEMM (R18 measured best) -------------
__global__ __launch_bounds__(512, 1) void gemm256p(
    const u16* __restrict__ A, const u16* __restrict__ Bt,
    const float* __restrict__ bias, u16* __restrict__ o0) {
  constexpr int K = 1024, N = 4096, NT = 16;
  __shared__ __align__(16) u16 lA[2 * 2 * 256 * 32];  // [buf][kh][256][32] 64KB
  __shared__ __align__(16) u16 lB[2 * 2 * 256 * 32];  // 64KB
  int tid = threadIdx.x;
  int lane = tid & 63, wid = tid >> 6;
  int lr = lane & 15, lg = lane >> 4;
  int wm = wid >> 2, wn = wid & 3;                    // 2M x 4N wave grid

  int gx = gridDim.x;                                 // 16
  int nwg = gx * gridDim.y;                           // 256 (%8==0)
  int bid = blockIdx.y * gx + blockIdx.x;
  int swz = (bid & 7) * (nwg >> 3) + (bid >> 3);
  int rowBase = (swz / gx) * 256, colBase = (swz % gx) * 256;

  int sr0 = tid >> 2, sc = (tid & 3) * 8;             // staging: 128 rows/round
  const u16* gA = A + (size_t)(rowBase + sr0) * K + sc;
  const u16* gB = Bt + (size_t)(colBase + sr0) * K + sc;
  u16* lAw = lA + wid * 512;                          // wave-uniform base
  u16* lBw = lB + wid * 512;

  auto stageA = [&](int t, int kh) {                  // 2 gl16 / thread
    int koff = t * 64 + kh * 32;
    u16* d = lAw + ((t & 1) * 2 + kh) * 8192;
    gl16(gA + koff, d);
    gl16(gA + (size_t)128 * K + koff, d + 4096);
  };
  auto stageB = [&](int t, int kh) {
    int koff = t * 64 + kh * 32;
    u16* d = lBw + ((t & 1) * 2 + kh) * 8192;
    gl16(gB + koff, d);
    gl16(gB + (size_t)128 * K + koff, d + 4096);
  };

  f32x4 acc[8][4];
  f32x4 zero = {0.f, 0.f, 0.f, 0.f};
#pragma unroll
  for (int m = 0; m < 8; m++)
#pragma unroll
    for (int n = 0; n < 4; n++) acc[m][n] = zero;

  bf16x8 aF[4][2], bF0[2][2], bF1[2][2];              // operand frags

  auto rdA = [&](int t, int rh) {                     // 8 ds_read_b128
#pragma unroll
    for (int kh = 0; kh < 2; kh++) {
      const u16* p = lA + ((t & 1) * 2 + kh) * 8192;
#pragma unroll
      for (int m = 0; m < 4; m++)
        aF[m][kh] = *(const bf16x8*)&p[(wm * 128 + rh * 64 + m * 16 + lr) * 32 + lg * 8];
    }
  };
  auto rdB = [&](bf16x8 (&bb)[2][2], int t, int ch) { // 4 ds_read_b128
#pragma unroll
    for (int kh = 0; kh < 2; kh++) {
      const u16* p = lB + ((t & 1) * 2 + kh) * 8192;
#pragma unroll
      for (int n = 0; n < 2; n++)
        bb[n][kh] = *(const bf16x8*)&p[(wn * 64 + ch * 32 + n * 16 + lr) * 32 + lg * 8];
    }
  };

  // prologue: tile 0 fully staged; retire A0,A1,B0 (B1 stays in flight)
  stageA(0, 0); stageA(0, 1); stageB(0, 0); stageB(0, 1);
  waitv<2>();
  barrier_f();

  for (int t = 0; t < NT; t++) {
    bool st = (t + 1 < NT);
    // ---- p1: quadrant (rh0, ch0) ----
    rdA(t, 0); rdB(bF0, t, 0);
    if (st) { stageA(t + 1, 0); stageA(t + 1, 1); }
    barrier_f(); lgkm0();
    __builtin_amdgcn_s_setprio(1);
#pragma unroll
    for (int m = 0; m < 4; m++)
#pragma unroll
      for (int n = 0; n < 2; n++)
#pragma unroll
        for (int kh = 0; kh < 2; kh++)
          acc[m][n] = __builtin_amdgcn_mfma_f32_16x16x32_bf16(bF0[n][kh], aF[m][kh], acc[m][n], 0, 0, 0);
    __builtin_amdgcn_s_setprio(0);
    if (st) waitv<4>(); else waitv<0>();  // retire B1(t)
    barrier_f();
    // ---- p2: quadrant (rh0, ch1) ----
    rdB(bF1, t, 1);
    if (st) stageB(t + 1, 0);
    barrier_f(); lgkm0();
    __builtin_amdgcn_s_setprio(1);
#pragma unroll
    for (int m = 0; m < 4; m++)
#pragma unroll
      for (int n = 0; n < 2; n++)
#pragma unroll
        for (int kh = 0; kh < 2; kh++)
          acc[m][2 + n] = __builtin_amdgcn_mfma_f32_16x16x32_bf16(bF1[n][kh], aF[m][kh], acc[m][2 + n], 0, 0, 0);
    __builtin_amdgcn_s_setprio(0);
    barrier_f();
    // ---- p3: quadrant (rh1, ch0) ----
    rdA(t, 1);
    if (st) stageB(t + 1, 1);
    barrier_f(); lgkm0();
    __builtin_amdgcn_s_setprio(1);
#pragma unroll
    for (int m = 0; m < 4; m++)
#pragma unroll
      for (int n = 0; n < 2; n++)
#pragma unroll
        for (int kh = 0; kh < 2; kh++)
          acc[4 + m][n] = __builtin_amdgcn_mfma_f32_16x16x32_bf16(bF0[n][kh], aF[m][kh], acc[4 + m][n], 0, 0, 0);
    __builtin_amdgcn_s_setprio(0);
    barrier_f();
    // ---- p4: quadrant (rh1, ch1) ----
    barrier_f(); lgkm0();
    __builtin_amdgcn_s_setprio(1);
#pragma unroll
    for (int m = 0; m < 4; m++)
#pragma unroll
      for (int n = 0; n < 2; n++)
#pragma unroll
        for (int kh = 0; kh < 2; kh++)
          acc[4 + m][2 + n] = __builtin_amdgcn_mfma_f32_16x16x32_bf16(bF1[n][kh], aF[m][kh], acc[4 + m][2 + n], 0, 0, 0);
    __builtin_amdgcn_s_setprio(0);
    if (st) waitv<2>();                   // retire A0,A1,B0 of t+1
    barrier_f();
  }

  // epilogue: lane holds C rows (wm*128 + mi*16 + lr), col quad (wn*64 + ni*16 + lg*4)
#pragma unroll
  for (int mi = 0; mi < 8; mi++) {
    int grow = rowBase + wm * 128 + mi * 16 + lr;
#pragma unroll
    for (int ni = 0; ni < 4; ni++) {
      int gcol = colBase + wn * 64 + ni * 16 + lg * 4;
      f32x4 v4 = acc[mi][ni];
      float4 bq = *(const float4*)&bias[gcol];
      s16x4 o4;
#pragma unroll
      for (int j = 0; j < 4; j++) {
        float g = v4[j] + ((const float*)&bq)[j];
        float e = __builtin_amdgcn_exp2f(2.302208198f * (g + 0.044715f * g * g * g));
        o4[j] = (short)f2bf(g - g * __builtin_amdgcn_rcpf(1.0f + e));
      }
      *(s16x4*)&o0[(size_t)grow * N + gcol] = o4;
    }
  }
}

// ---- Flash attention: block = (b, h, 128 q-rows); 4 waves x 32 rows -------
// R15 version (measured best): exp2-domain scores, NO max tracking.
__global__ __launch_bounds__(256) void attn_kernel(const u16* __restrict__ q,
                                                   const u16* __restrict__ k,
                                                   const u16* __restrict__ vt,
                                                   u16* __restrict__ o) {
  __shared__ __align__(16) u16 lK[64 * 64];
  __shared__ __align__(16) u16 lV[64 * 64];
  __shared__ __align__(16) u16 lP[4 * 2 * 16 * 64];
  const int S = 2048, E = 1024;
  int qt = blockIdx.x, h = blockIdx.y, b = blockIdx.z;
  int tid = threadIdx.x, wid = tid >> 6, lane = tid & 63;
  int lr = lane & 15, lg = lane >> 4;
  u16* lPw = &lP[wid * 2048];

  const u16* qp = q + ((size_t)b * S + qt * 128 + wid * 32) * E + h * 64;
  const u16* kp = k + (size_t)b * S * E + h * 64;
  const u16* vp = vt + ((size_t)(b * 16 + h) * 64) * S;

  bf16x8 aQ[2][2];
#pragma unroll
  for (int m = 0; m < 2; m++)
#pragma unroll
    for (int kk = 0; kk < 2; kk++)
      aQ[m][kk] = *(const bf16x8*)(qp + (size_t)(m * 16 + lr) * E + kk * 32 + lg * 8);

  bf16x8 onesv;
#pragma unroll
  for (int i = 0; i < 8; i++) onesv[i] = (short)0x3F80;

  f32x4 accO[2][4], accL[2];
  f32x4 zero = {0.f, 0.f, 0.f, 0.f};
#pragma unroll
  for (int m = 0; m < 2; m++) {
    accL[m] = zero;
#pragma unroll
    for (int nn = 0; nn < 4; nn++) accO[m][nn] = zero;
  }

  int sr_ = tid >> 3, sc_ = (tid & 7) * 8;
  const u16* kps0 = kp + (size_t)sr_ * E + sc_;
  const u16* kps1 = kp + (size_t)(sr_ + 32) * E + sc_;
  const u16* vps0 = vp + (size_t)sr_ * S + sc_;
  const u16* vps1 = vp + (size_t)(sr_ + 32) * S + sc_;

  bf16x8 rk0 = *(const bf16x8*)(kps0);
  bf16x8 rk1 = *(const bf16x8*)(kps1);
  bf16x8 rv0 = *(const bf16x8*)(vps0);
  bf16x8 rv1 = *(const bf16x8*)(vps1);

  for (int kv0 = 0; kv0 < S; kv0 += 64) {
    __syncthreads();
    *(bf16x8*)&lK[swzi(sr_, sc_)] = rk0;
    *(bf16x8*)&lK[swzi(32 + sr_, sc_)] = rk1;
    *(bf16x8*)&lV[swzi(sr_, sc_)] = rv0;
    *(bf16x8*)&lV[swzi(32 + sr_, sc_)] = rv1;
    int nx = kv0 + 64;
    if (nx < S) {
      rk0 = *(const bf16x8*)(kps0 + (size_t)nx * E);
      rk1 = *(const bf16x8*)(kps1 + (size_t)nx * E);
      rv0 = *(const bf16x8*)(vps0 + nx);
      rv1 = *(const bf16x8*)(vps1 + nx);
    }
    __syncthreads();

    f32x4 sc4[2][4];
#pragma unroll
    for (int m = 0; m < 2; m++)
#pragma unroll
      for (int n = 0; n < 4; n++) sc4[m][n] = zero;
#pragma unroll
    for (int n = 0; n < 4; n++) {
      bf16x8 bk0 = *(const bf16x8*)&lK[swzi(n * 16 + lr, lg * 8)];
      bf16x8 bk1 = *(const bf16x8*)&lK[swzi(n * 16 + lr, 32 + lg * 8)];
#pragma unroll
      for (int m = 0; m < 2; m++) {
        sc4[m][n] = __builtin_amdgcn_mfma_f32_16x16x32_bf16(bk0, aQ[m][0], sc4[m][n], 0, 0, 0);
        sc4[m][n] = __builtin_amdgcn_mfma_f32_16x16x32_bf16(bk1, aQ[m][1], sc4[m][n], 0, 0, 0);
      }
    }

#pragma unroll
    for (int m = 0; m < 2; m++)
#pragma unroll
      for (int n = 0; n < 4; n++) {
        s16x4 pq;
#pragma unroll
        for (int j = 0; j < 4; j++)
          pq[j] = (short)f2bf_tr(__builtin_amdgcn_exp2f(sc4[m][n][j]));
        *(s16x4*)&lPw[m * 1024 + swzi(lr, n * 16 + lg * 4)] = pq;
      }

#pragma unroll
    for (int kk = 0; kk < 2; kk++) {
      bf16x8 ap[2];
#pragma unroll
      for (int m = 0; m < 2; m++)
        ap[m] = *(const bf16x8*)&lPw[m * 1024 + swzi(lr, kk * 32 + lg * 8)];
#pragma unroll
      for (int m = 0; m < 2; m++)
        accL[m] = __builtin_amdgcn_mfma_f32_16x16x32_bf16(onesv, ap[m], accL[m], 0, 0, 0);
#pragma unroll
      for (int nn = 0; nn < 4; nn++) {
        bf16x8 bv = *(const bf16x8*)&lV[swzi(nn * 16 + lr, kk * 32 + lg * 8)];
#pragma unroll
        for (int m = 0; m < 2; m++)
          accO[m][nn] = __builtin_amdgcn_mfma_f32_16x16x32_bf16(bv, ap[m], accO[m][nn], 0, 0, 0);
      }
    }
  }

#pragma unroll
  for (int m = 0; m < 2; m++) {
    float inv = 1.0f / accL[m][0];
    int srow = qt * 128 + wid * 32 + m * 16 + lr;
#pragma unroll
    for (int nn = 0; nn < 4; nn++) {
      s16x4 o4;
#pragma unroll
      for (int j = 0; j < 4; j++) o4[j] = (short)f2bf(accO[m][nn][j] * inv);
      *(s16x4*)&o[((size_t)b * S + srow) * E + h * 64 + nn * 16 + lg * 4] = o4;
    }
  }
}

// ---------------------------------------------------------------------------
extern "C" void kernel_launch(void* const* d_in, const int* in_sizes, int n_in,
                              void* d_out, int out_size, void* d_ws, size_t ws_size,
                              hipStream_t stream) {
  (void)in_sizes; (void)n_in; (void)out_size; (void)ws_size;
  const float* x     = (const float*)d_in[0];
  const float* w_qkv = (const float*)d_in[1];
  const float* w_fc  = (const float*)d_in[2];
  const float* w1    = (const float*)d_in[3];
  const float* b1    = (const float*)d_in[4];
  const float* w2    = (const float*)d_in[5];
  const float* b2    = (const float*)d_in[6];
  float* out = (float*)d_out;
  char* ws = (char*)d_ws;

  // workspace layout (80 MB total)
  u16* wqkvT = (u16*)(ws);                  // [3072][1024] 6 MB
  u16* wfcT  = (u16*)(ws + 6291456);        // [1024][1024] 2 MB
  u16* w1T   = (u16*)(ws + 8388608);        // [4096][1024] 8 MB
  u16* w2T   = (u16*)(ws + 16777216);       // [1024][4096] 8 MB
  u16* hbuf  = (u16*)(ws + 25165824);       // h1 -> attnout -> h2, 8 MB
  u16* qbuf  = (u16*)(ws + 33554432);       // 8 MB
  u16* kbuf  = (u16*)(ws + 41943040);       // 8 MB
  u16* vtbuf = (u16*)(ws + 58720256);       // 8 MB (written directly by qkv)
  float* x2  = (float*)(ws + 67108864);     // 16 MB f32
  u16* act   = qbuf;                        // [4096][4096] 32 MB over q..vt (dead)

  wcastT_all<<<12288, 256, 0, stream>>>(w_qkv, w_fc, w1, w2,
                                        wqkvT, wfcT, w1T, w2T);

  ln_kernel<<<4096, 256, 0, stream>>>(x, hbuf);
  gemm_bt<0, 128, 32><<<dim3(24, 32), 256, 0, stream>>>(hbuf, wqkvT, 3072, 1024,
                                                        nullptr, nullptr, nullptr,
                                                        qbuf, kbuf, vtbuf);
  attn_kernel<<<dim3(16, 16, 2), 256, 0, stream>>>(qbuf, kbuf, vtbuf, hbuf);
  gemm_bt<1, 64, 64><<<dim3(8, 64), 256, 0, stream>>>(hbuf, wfcT, 1024, 1024,
                                                      x, nullptr, x2,
                                                      nullptr, nullptr, nullptr);
  ln_kernel<<<4096, 256, 0, stream>>>(x2, hbuf);
  gemm256p<<<dim3(16, 16), 512, 0, stream>>>(hbuf, w1T, b1, act);
  gemm_bt<3, 64, 64><<<dim3(8, 64), 256, 0, stream>>>(act, w2T, 1024, 4096,
                                                      x2, b2, out,
                                                      nullptr, nullptr, nullptr);
}

// Round 23
// 226.118 us; speedup vs baseline: 1.0791x; 1.0127x over previous
//
#include <hip/hip_runtime.h>

typedef unsigned short u16;
typedef __attribute__((ext_vector_type(8))) short bf16x8;   // 8 x bf16 (4 VGPRs)
typedef __attribute__((ext_vector_type(4))) short s16x4;
typedef __attribute__((ext_vector_type(4))) float f32x4;

#define DEV __device__ __forceinline__

DEV u16 f2bf(float f) {                       // fp32 -> bf16 bits, RNE
  union { float f; unsigned u; } v; v.f = f;
  unsigned r = v.u + 0x7fffu + ((v.u >> 16) & 1u);
  return (u16)(r >> 16);
}
DEV u16 f2bf_tr(float f) {                    // truncating (P only; bias cancels in O/l)
  union { float f; unsigned u; } v; v.f = f;
  return (u16)(v.u >> 16);
}

// XOR bank-swizzle for a 64-col bf16 LDS tile (u16 index units).
DEV int swzi(int row, int col) { return row * 64 + (col ^ ((row & 7) << 3)); }

// async global->LDS, 16B per lane. LDS dest is wave-uniform base; HW adds lane*16.
DEV void gl16(const u16* g, u16* l) {
  __builtin_amdgcn_global_load_lds((const __attribute__((address_space(1))) void*)g,
                                   (__attribute__((address_space(3))) void*)l, 16, 0, 0);
}

template <int N> DEV void waitv() {           // counted vmcnt (compile-time imm)
  asm volatile("s_waitcnt vmcnt(%0)" :: "n"(N) : "memory");
}
DEV void barrier_f() {
  __builtin_amdgcn_s_barrier();
  asm volatile("" ::: "memory");
}
DEV void lgkm0() { asm volatile("s_waitcnt lgkmcnt(0)" ::: "memory"); }

// ---- fused weight cast+transpose for ALL four weights: one dispatch -------
// segments: [0,3072) w_qkv 1024x3072; [3072,4096) w_fc 1024x1024;
//           [4096,8192) w1 1024x4096; [8192,12288) w2 4096x1024.
__global__ __launch_bounds__(256) void wcastT_all(
    const float* __restrict__ w_qkv, const float* __restrict__ w_fc,
    const float* __restrict__ w1, const float* __restrict__ w2,
    u16* __restrict__ wqkvT, u16* __restrict__ wfcT,
    u16* __restrict__ w1T, u16* __restrict__ w2T) {
  int bid = blockIdx.x;
  const float* w; u16* wt; int K, N, nx, t;
  if (bid < 3072)      { w = w_qkv; wt = wqkvT; K = 1024; N = 3072; nx = 96;  t = bid; }
  else if (bid < 4096) { w = w_fc;  wt = wfcT;  K = 1024; N = 1024; nx = 32;  t = bid - 3072; }
  else if (bid < 8192) { w = w1;    wt = w1T;   K = 1024; N = 4096; nx = 128; t = bid - 4096; }
  else                 { w = w2;    wt = w2T;   K = 4096; N = 1024; nx = 32;  t = bid - 8192; }
  int n0 = (t % nx) * 32, k0 = (t / nx) * 32;

  __shared__ float tl[32][33];
  int tx = threadIdx.x & 31, ty = threadIdx.x >> 5;
#pragma unroll
  for (int i = 0; i < 32; i += 8)
    tl[ty + i][tx] = w[(size_t)(k0 + ty + i) * N + n0 + tx];
  __syncthreads();
#pragma unroll
  for (int i = 0; i < 32; i += 8)
    wt[(size_t)(n0 + ty + i) * K + k0 + tx] = f2bf(tl[tx][ty + i]);
}

// ---- LayerNorm (1024 cols, no affine) f32 -> bf16 -------------------------
__global__ __launch_bounds__(256) void ln_kernel(const float* __restrict__ x,
                                                 u16* __restrict__ out) {
  int row = blockIdx.x, tid = threadIdx.x;
  const float4* xr = (const float4*)(x + (size_t)row * 1024);
  float4 f = xr[tid];
  float s = f.x + f.y + f.z + f.w;
  float s2 = f.x * f.x + f.y * f.y + f.z * f.z + f.w * f.w;
#pragma unroll
  for (int o = 1; o < 64; o <<= 1) { s += __shfl_xor(s, o); s2 += __shfl_xor(s2, o); }
  __shared__ float red[2][4];
  int wid = tid >> 6;
  if ((tid & 63) == 0) { red[0][wid] = s; red[1][wid] = s2; }
  __syncthreads();
  float tot  = red[0][0] + red[0][1] + red[0][2] + red[0][3];
  float tot2 = red[1][0] + red[1][1] + red[1][2] + red[1][3];
  float mu = tot * (1.0f / 1024.0f);
  float var = tot2 * (1.0f / 1024.0f) - mu * mu;
  float rstd = rsqrtf(var + 1e-5f);
  s16x4 o4;
  o4[0] = (short)f2bf((f.x - mu) * rstd);
  o4[1] = (short)f2bf((f.y - mu) * rstd);
  o4[2] = (short)f2bf((f.z - mu) * rstd);
  o4[3] = (short)f2bf((f.w - mu) * rstd);
  *(s16x4*)(out + (size_t)row * 1024 + tid * 4) = o4;
}

// ---- GEMM: C[M,N] = A[M,K](bf16) * Bt[N,K]^T(bf16), fused epilogues -------
// R15/R17-proven structure (session best). qkv BM=128/BK=32; fc/mlp2 64/64.
// MODE 0: qkv split -> q(o0, pre-scaled 0.125*log2e), k(o1), V^T direct (o2)
// MODE 1: outF = resid + C (f32)        MODE 3: outF = resid + bias + C
template <int MODE, int BM, int BK>
__global__ __launch_bounds__(256) void gemm_bt(
    const u16* __restrict__ A, const u16* __restrict__ Bt, int N, int K,
    const float* __restrict__ resid, const float* __restrict__ bias,
    float* __restrict__ outF, u16* __restrict__ o0, u16* __restrict__ o1,
    u16* __restrict__ o2) {
  constexpr int MR = BM / 32;
  constexpr int KH = BK / 32;
  constexpr int LDEPTH = KH * (BM / 64 + 2);
  constexpr int ACH = BM * 32, BCH = 128 * 32;
  __shared__ __align__(16) u16 lA[2 * KH * ACH];
  __shared__ __align__(16) u16 lB[2 * KH * BCH];
  int tid = threadIdx.x;
  int lane = tid & 63, wid = tid >> 6;
  int lr = lane & 15, lg = lane >> 4;

  int gx = gridDim.x;
  int nwg = gx * gridDim.y;
  int bid = blockIdx.y * gx + blockIdx.x;
  int swz = (bid & 7) * (nwg >> 3) + (bid >> 3);
  int rowBase = (swz / gx) * BM, colBase = (swz % gx) * 128;
  int wr = (wid >> 1) * (MR * 16), wc = (wid & 1) * 64;

  int srow = wid * 16 + (lane >> 2);
  int scol = (lane & 3) * 8;
  const u16* gA = A + (size_t)(rowBase + srow) * K + scol;
  const u16* gB = Bt + (size_t)(colBase + srow) * K + scol;
  u16* lAb = &lA[wid * 16 * 32];
  u16* lBb = &lB[wid * 16 * 32];

  auto stage = [&](int t, int buf) {
    int k0 = t * BK;
#pragma unroll
    for (int kk = 0; kk < KH; kk++) {
      u16* dA = lAb + buf * KH * ACH + kk * ACH;
      u16* dB = lBb + buf * KH * BCH + kk * BCH;
      int koff = k0 + kk * 32;
#pragma unroll
      for (int c = 0; c < BM / 64; c++)
        gl16(gA + (size_t)c * 64 * K + koff, dA + c * 64 * 32);
#pragma unroll
      for (int c = 0; c < 2; c++)
        gl16(gB + (size_t)c * 64 * K + koff, dB + c * 64 * 32);
    }
  };

  f32x4 acc[MR][4];
  f32x4 zero = {0.f, 0.f, 0.f, 0.f};
#pragma unroll
  for (int m = 0; m < MR; m++)
#pragma unroll
    for (int n = 0; n < 4; n++) acc[m][n] = zero;

  stage(0, 0);

  int nt = K / BK;
  for (int t = 0; t < nt; t++) {
    int cur = t & 1;
    if (t + 1 < nt) {
      stage(t + 1, cur ^ 1);
      waitv<LDEPTH>();
    } else {
      waitv<0>();
    }
    barrier_f();

    const u16* cA = &lA[cur * KH * ACH];
    const u16* cB = &lB[cur * KH * BCH];
#pragma unroll
    for (int kk = 0; kk < KH; kk++) {
      bf16x8 af[MR], bfv[4];
#pragma unroll
      for (int m = 0; m < MR; m++)
        af[m] = *(const bf16x8*)&cA[kk * ACH + (wr + m * 16 + lr) * 32 + lg * 8];
#pragma unroll
      for (int n = 0; n < 4; n++)
        bfv[n] = *(const bf16x8*)&cB[kk * BCH + (wc + n * 16 + lr) * 32 + lg * 8];
#pragma unroll
      for (int m = 0; m < MR; m++)
#pragma unroll
        for (int n = 0; n < 4; n++)
          acc[m][n] = __builtin_amdgcn_mfma_f32_16x16x32_bf16(bfv[n], af[m], acc[m][n], 0, 0, 0);
    }
    barrier_f();
  }

#pragma unroll
  for (int m = 0; m < MR; m++) {
    int grow = rowBase + wr + m * 16 + lr;
#pragma unroll
    for (int n = 0; n < 4; n++) {
      int gcol = colBase + wc + n * 16 + lg * 4;
      f32x4 v4 = acc[m][n];
      if constexpr (MODE == 0) {
        if (gcol < 2048) {
          bool isq = gcol < 1024;
          u16* dst = isq ? o0 : o1;
          s16x4 o4;
#pragma unroll
          for (int j = 0; j < 4; j++)
            o4[j] = (short)f2bf(isq ? v4[j] * 0.18033688011112042f : v4[j]);
          *(s16x4*)&dst[(size_t)grow * 1024 + (gcol & 1023)] = o4;
        } else {
          int c = gcol - 2048;
          int bb = grow >> 11, ss = grow & 2047;
          size_t vbase = ((size_t)bb * 1024 + c) * 2048 + ss;
#pragma unroll
          for (int j = 0; j < 4; j++)
            o2[vbase + (size_t)j * 2048] = f2bf(v4[j]);
        }
      } else if constexpr (MODE == 1) {
        size_t idx = (size_t)grow * N + gcol;
        float4 r = *(const float4*)&resid[idx];
        float4 ov = {r.x + v4[0], r.y + v4[1], r.z + v4[2], r.w + v4[3]};
        *(float4*)&outF[idx] = ov;
      } else {
        size_t idx = (size_t)grow * N + gcol;
        float4 r = *(const float4*)&resid[idx];
        float4 bq = *(const float4*)&bias[gcol];
        float4 ov = {r.x + bq.x + v4[0], r.y + bq.y + v4[1],
                     r.z + bq.z + v4[2], r.w + bq.w + v4[3]};
        *(float4*)&outF[idx] = ov;
      }
    }
  }
}

// ---- mlp1: 256x256 4-phase pipelined GEMM (R18 measured best) -------------
__global__ __launch_bounds__(512, 1) void gemm256p(
    const u16* __restrict__ A, const u16* __restrict__ Bt,
    const float* __restrict__ bias, u16* __restrict__ o0) {
  constexpr int K = 1024, N = 4096, NT = 16;
  __shared__ __align__(16) u16 lA[2 * 2 * 256 * 32];  // [buf][kh][256][32] 64KB
  __shared__ __align__(16) u16 lB[2 * 2 * 256 * 32];  // 64KB
  int tid = threadIdx.x;
  int lane = tid & 63, wid = tid >> 6;
  int lr = lane & 15, lg = lane >> 4;
  int wm = wid >> 2, wn = wid & 3;                    // 2M x 4N wave grid

  int gx = gridDim.x;                                 // 16
  int nwg = gx * gridDim.y;                           // 256 (%8==0)
  int bid = blockIdx.y * gx + blockIdx.x;
  int swz = (bid & 7) * (nwg >> 3) + (bid >> 3);
  int rowBase = (swz / gx) * 256, colBase = (swz % gx) * 256;

  int sr0 = tid >> 2, sc = (tid & 3) * 8;             // staging: 128 rows/round
  const u16* gA = A + (size_t)(rowBase + sr0) * K + sc;
  const u16* gB = Bt + (size_t)(colBase + sr0) * K + sc;
  u16* lAw = lA + wid * 512;                          // wave-uniform base
  u16* lBw = lB + wid * 512;

  auto stageA = [&](int t, int kh) {                  // 2 gl16 / thread
    int koff = t * 64 + kh * 32;
    u16* d = lAw + ((t & 1) * 2 + kh) * 8192;
    gl16(gA + koff, d);
    gl16(gA + (size_t)128 * K + koff, d + 4096);
  };
  auto stageB = [&](int t, int kh) {
    int koff = t * 64 + kh * 32;
    u16* d = lBw + ((t & 1) * 2 + kh) * 8192;
    gl16(gB + koff, d);
    gl16(gB + (size_t)128 * K + koff, d + 4096);
  };

  f32x4 acc[8][4];
  f32x4 zero = {0.f, 0.f, 0.f, 0.f};
#pragma unroll
  for (int m = 0; m < 8; m++)
#pragma unroll
    for (int n = 0; n < 4; n++) acc[m][n] = zero;

  bf16x8 aF[4][2], bF0[2][2], bF1[2][2];              // operand frags

  auto rdA = [&](int t, int rh) {                     // 8 ds_read_b128
#pragma unroll
    for (int kh = 0; kh < 2; kh++) {
      const u16* p = lA + ((t & 1) * 2 + kh) * 8192;
#pragma unroll
      for (int m = 0; m < 4; m++)
        aF[m][kh] = *(const bf16x8*)&p[(wm * 128 + rh * 64 + m * 16 + lr) * 32 + lg * 8];
    }
  };
  auto rdB = [&](bf16x8 (&bb)[2][2], int t, int ch) { // 4 ds_read_b128
#pragma unroll
    for (int kh = 0; kh < 2; kh++) {
      const u16* p = lB + ((t & 1) * 2 + kh) * 8192;
#pragma unroll
      for (int n = 0; n < 2; n++)
        bb[n][kh] = *(const bf16x8*)&p[(wn * 64 + ch * 32 + n * 16 + lr) * 32 + lg * 8];
    }
  };

  // prologue: tile 0 fully staged; retire A0,A1,B0 (B1 stays in flight)
  stageA(0, 0); stageA(0, 1); stageB(0, 0); stageB(0, 1);
  waitv<2>();
  barrier_f();

  for (int t = 0; t < NT; t++) {
    bool st = (t + 1 < NT);
    // ---- p1: quadrant (rh0, ch0) ----
    rdA(t, 0); rdB(bF0, t, 0);
    if (st) { stageA(t + 1, 0); stageA(t + 1, 1); }
    barrier_f(); lgkm0();
    __builtin_amdgcn_s_setprio(1);
#pragma unroll
    for (int m = 0; m < 4; m++)
#pragma unroll
      for (int n = 0; n < 2; n++)
#pragma unroll
        for (int kh = 0; kh < 2; kh++)
          acc[m][n] = __builtin_amdgcn_mfma_f32_16x16x32_bf16(bF0[n][kh], aF[m][kh], acc[m][n], 0, 0, 0);
    __builtin_amdgcn_s_setprio(0);
    if (st) waitv<4>(); else waitv<0>();  // retire B1(t)
    barrier_f();
    // ---- p2: quadrant (rh0, ch1) ----
    rdB(bF1, t, 1);
    if (st) stageB(t + 1, 0);
    barrier_f(); lgkm0();
    __builtin_amdgcn_s_setprio(1);
#pragma unroll
    for (int m = 0; m < 4; m++)
#pragma unroll
      for (int n = 0; n < 2; n++)
#pragma unroll
        for (int kh = 0; kh < 2; kh++)
          acc[m][2 + n] = __builtin_amdgcn_mfma_f32_16x16x32_bf16(bF1[n][kh], aF[m][kh], acc[m][2 + n], 0, 0, 0);
    __builtin_amdgcn_s_setprio(0);
    barrier_f();
    // ---- p3: quadrant (rh1, ch0) ----
    rdA(t, 1);
    if (st) stageB(t + 1, 1);
    barrier_f(); lgkm0();
    __builtin_amdgcn_s_setprio(1);
#pragma unroll
    for (int m = 0; m < 4; m++)
#pragma unroll
      for (int n = 0; n < 2; n++)
#pragma unroll
        for (int kh = 0; kh < 2; kh++)
          acc[4 + m][n] = __builtin_amdgcn_mfma_f32_16x16x32_bf16(bF0[n][kh], aF[m][kh], acc[4 + m][n], 0, 0, 0);
    __builtin_amdgcn_s_setprio(0);
    barrier_f();
    // ---- p4: quadrant (rh1, ch1) ----
    barrier_f(); lgkm0();
    __builtin_amdgcn_s_setprio(1);
#pragma unroll
    for (int m = 0; m < 4; m++)
#pragma unroll
      for (int n = 0; n < 2; n++)
#pragma unroll
        for (int kh = 0; kh < 2; kh++)
          acc[4 + m][2 + n] = __builtin_amdgcn_mfma_f32_16x16x32_bf16(bF1[n][kh], aF[m][kh], acc[4 + m][2 + n], 0, 0, 0);
    __builtin_amdgcn_s_setprio(0);
    if (st) waitv<2>();                   // retire A0,A1,B0 of t+1
    barrier_f();
  }

  // epilogue: lane holds C rows (wm*128 + mi*16 + lr), col quad (wn*64 + ni*16 + lg*4)
#pragma unroll
  for (int mi = 0; mi < 8; mi++) {
    int grow = rowBase + wm * 128 + mi * 16 + lr;
#pragma unroll
    for (int ni = 0; ni < 4; ni++) {
      int gcol = colBase + wn * 64 + ni * 16 + lg * 4;
      f32x4 v4 = acc[mi][ni];
      float4 bq = *(const float4*)&bias[gcol];
      s16x4 o4;
#pragma unroll
      for (int j = 0; j < 4; j++) {
        float g = v4[j] + ((const float*)&bq)[j];
        float e = __builtin_amdgcn_exp2f(2.302208198f * (g + 0.044715f * g * g * g));
        o4[j] = (short)f2bf(g - g * __builtin_amdgcn_rcpf(1.0f + e));
      }
      *(s16x4*)&o0[(size_t)grow * N + gcol] = o4;
    }
  }
}

// ---- Flash attention: block = (b, h, 128 q-rows); 4 waves x 32 rows -------
// R15 math (exp2-domain, no max tracking) + DOUBLE-BUFFERED lK/lV: one
// barrier per KV tile (writes(t)->buf t&1 occur after barrier(t-1), which
// orders them after all iter-(t-2) reads of that buf -> WAR safe; the single
// barrier provides write visibility). Per-wave lP unchanged (in-wave order).
__global__ __launch_bounds__(256) void attn_kernel(const u16* __restrict__ q,
                                                   const u16* __restrict__ k,
                                                   const u16* __restrict__ vt,
                                                   u16* __restrict__ o) {
  __shared__ __align__(16) u16 lK[2][64 * 64];
  __shared__ __align__(16) u16 lV[2][64 * 64];
  __shared__ __align__(16) u16 lP[4 * 2 * 16 * 64];
  const int S = 2048, E = 1024;
  int qt = blockIdx.x, h = blockIdx.y, b = blockIdx.z;
  int tid = threadIdx.x, wid = tid >> 6, lane = tid & 63;
  int lr = lane & 15, lg = lane >> 4;
  u16* lPw = &lP[wid * 2048];

  const u16* qp = q + ((size_t)b * S + qt * 128 + wid * 32) * E + h * 64;
  const u16* kp = k + (size_t)b * S * E + h * 64;
  const u16* vp = vt + ((size_t)(b * 16 + h) * 64) * S;

  bf16x8 aQ[2][2];
#pragma unroll
  for (int m = 0; m < 2; m++)
#pragma unroll
    for (int kk = 0; kk < 2; kk++)
      aQ[m][kk] = *(const bf16x8*)(qp + (size_t)(m * 16 + lr) * E + kk * 32 + lg * 8);

  bf16x8 onesv;
#pragma unroll
  for (int i = 0; i < 8; i++) onesv[i] = (short)0x3F80;

  f32x4 accO[2][4], accL[2];
  f32x4 zero = {0.f, 0.f, 0.f, 0.f};
#pragma unroll
  for (int m = 0; m < 2; m++) {
    accL[m] = zero;
#pragma unroll
    for (int nn = 0; nn < 4; nn++) accO[m][nn] = zero;
  }

  int sr_ = tid >> 3, sc_ = (tid & 7) * 8;
  const u16* kps0 = kp + (size_t)sr_ * E + sc_;
  const u16* kps1 = kp + (size_t)(sr_ + 32) * E + sc_;
  const u16* vps0 = vp + (size_t)sr_ * S + sc_;
  const u16* vps1 = vp + (size_t)(sr_ + 32) * S + sc_;

  bf16x8 rk0 = *(const bf16x8*)(kps0);
  bf16x8 rk1 = *(const bf16x8*)(kps1);
  bf16x8 rv0 = *(const bf16x8*)(vps0);
  bf16x8 rv1 = *(const bf16x8*)(vps1);

  for (int kv0 = 0; kv0 < S; kv0 += 64) {
    int buf = (kv0 >> 6) & 1;
    u16* bK = lK[buf];
    u16* bV = lV[buf];
    *(bf16x8*)&bK[swzi(sr_, sc_)] = rk0;
    *(bf16x8*)&bK[swzi(32 + sr_, sc_)] = rk1;
    *(bf16x8*)&bV[swzi(sr_, sc_)] = rv0;
    *(bf16x8*)&bV[swzi(32 + sr_, sc_)] = rv1;
    int nx = kv0 + 64;
    if (nx < S) {                               // issue-early: next tile -> regs
      rk0 = *(const bf16x8*)(kps0 + (size_t)nx * E);
      rk1 = *(const bf16x8*)(kps1 + (size_t)nx * E);
      rv0 = *(const bf16x8*)(vps0 + nx);
      rv1 = *(const bf16x8*)(vps1 + nx);
    }
    __syncthreads();                            // writes to buf visible

    f32x4 sc4[2][4];
#pragma unroll
    for (int m = 0; m < 2; m++)
#pragma unroll
      for (int n = 0; n < 4; n++) sc4[m][n] = zero;
#pragma unroll
    for (int n = 0; n < 4; n++) {
      bf16x8 bk0 = *(const bf16x8*)&bK[swzi(n * 16 + lr, lg * 8)];
      bf16x8 bk1 = *(const bf16x8*)&bK[swzi(n * 16 + lr, 32 + lg * 8)];
#pragma unroll
      for (int m = 0; m < 2; m++) {
        sc4[m][n] = __builtin_amdgcn_mfma_f32_16x16x32_bf16(bk0, aQ[m][0], sc4[m][n], 0, 0, 0);
        sc4[m][n] = __builtin_amdgcn_mfma_f32_16x16x32_bf16(bk1, aQ[m][1], sc4[m][n], 0, 0, 0);
      }
    }

#pragma unroll
    for (int m = 0; m < 2; m++)
#pragma unroll
      for (int n = 0; n < 4; n++) {
        s16x4 pq;
#pragma unroll
        for (int j = 0; j < 4; j++)
          pq[j] = (short)f2bf_tr(__builtin_amdgcn_exp2f(sc4[m][n][j]));
        *(s16x4*)&lPw[m * 1024 + swzi(lr, n * 16 + lg * 4)] = pq;
      }

#pragma unroll
    for (int kk = 0; kk < 2; kk++) {
      bf16x8 ap[2];
#pragma unroll
      for (int m = 0; m < 2; m++)
        ap[m] = *(const bf16x8*)&lPw[m * 1024 + swzi(lr, kk * 32 + lg * 8)];
#pragma unroll
      for (int m = 0; m < 2; m++)
        accL[m] = __builtin_amdgcn_mfma_f32_16x16x32_bf16(onesv, ap[m], accL[m], 0, 0, 0);
#pragma unroll
      for (int nn = 0; nn < 4; nn++) {
        bf16x8 bv = *(const bf16x8*)&bV[swzi(nn * 16 + lr, kk * 32 + lg * 8)];
#pragma unroll
        for (int m = 0; m < 2; m++)
          accO[m][nn] = __builtin_amdgcn_mfma_f32_16x16x32_bf16(bv, ap[m], accO[m][nn], 0, 0, 0);
      }
    }
  }

#pragma unroll
  for (int m = 0; m < 2; m++) {
    float inv = 1.0f / accL[m][0];
    int srow = qt * 128 + wid * 32 + m * 16 + lr;
#pragma unroll
    for (int nn = 0; nn < 4; nn++) {
      s16x4 o4;
#pragma unroll
      for (int j = 0; j < 4; j++) o4[j] = (short)f2bf(accO[m][nn][j] * inv);
      *(s16x4*)&o[((size_t)b * S + srow) * E + h * 64 + nn * 16 + lg * 4] = o4;
    }
  }
}

// ---------------------------------------------------------------------------
extern "C" void kernel_launch(void* const* d_in, const int* in_sizes, int n_in,
                              void* d_out, int out_size, void* d_ws, size_t ws_size,
                              hipStream_t stream) {
  (void)in_sizes; (void)n_in; (void)out_size; (void)ws_size;
  const float* x     = (const float*)d_in[0];
  const float* w_qkv = (const float*)d_in[1];
  const float* w_fc  = (const float*)d_in[2];
  const float* w1    = (const float*)d_in[3];
  const float* b1    = (const float*)d_in[4];
  const float* w2    = (const float*)d_in[5];
  const float* b2    = (const float*)d_in[6];
  float* out = (float*)d_out;
  char* ws = (char*)d_ws;

  // workspace layout (80 MB total)
  u16* wqkvT = (u16*)(ws);                  // [3072][1024] 6 MB
  u16* wfcT  = (u16*)(ws + 6291456);        // [1024][1024] 2 MB
  u16* w1T   = (u16*)(ws + 8388608);        // [4096][1024] 8 MB
  u16* w2T   = (u16*)(ws + 16777216);       // [1024][4096] 8 MB
  u16* hbuf  = (u16*)(ws + 25165824);       // h1 -> attnout -> h2, 8 MB
  u16* qbuf  = (u16*)(ws + 33554432);       // 8 MB
  u16* kbuf  = (u16*)(ws + 41943040);       // 8 MB
  u16* vtbuf = (u16*)(ws + 58720256);       // 8 MB (written directly by qkv)
  float* x2  = (float*)(ws + 67108864);     // 16 MB f32
  u16* act   = qbuf;                        // [4096][4096] 32 MB over q..vt (dead)

  wcastT_all<<<12288, 256, 0, stream>>>(w_qkv, w_fc, w1, w2,
                                        wqkvT, wfcT, w1T, w2T);

  ln_kernel<<<4096, 256, 0, stream>>>(x, hbuf);
  gemm_bt<0, 128, 32><<<dim3(24, 32), 256, 0, stream>>>(hbuf, wqkvT, 3072, 1024,
                                                        nullptr, nullptr, nullptr,
                                                        qbuf, kbuf, vtbuf);
  attn_kernel<<<dim3(16, 16, 2), 256, 0, stream>>>(qbuf, kbuf, vtbuf, hbuf);
  gemm_bt<1, 64, 64><<<dim3(8, 64), 256, 0, stream>>>(hbuf, wfcT, 1024, 1024,
                                                      x, nullptr, x2,
                                                      nullptr, nullptr, nullptr);
  ln_kernel<<<4096, 256, 0, stream>>>(x2, hbuf);
  gemm256p<<<dim3(16, 16), 512, 0, stream>>>(hbuf, w1T, b1, act);
  gemm_bt<3, 64, 64><<<dim3(8, 64), 256, 0, stream>>>(act, w2T, 1024, 4096,
                                                      x2, b2, out,
                                                      nullptr, nullptr, nullptr);
}